// Round 9
// baseline (515.884 us; speedup 1.0000x reference)
//
#include <hip/hip_runtime.h>

#define NN 50000
#define NE 800000
#define NB 128
#define FIN 30
#define H 64
#define NC 10
#define L 3

#define BNODES 128            // nodes per bucket
#define NBKT 391              // ceil(NN / BNODES)
#define CAPB 3072             // edge capacity per bucket (lambda=2048, +22 sigma)

typedef unsigned int uint;
typedef unsigned short ushort;
typedef __attribute__((ext_vector_type(8))) short bf16x8;
typedef __attribute__((ext_vector_type(4))) float f32x4;

// f32 -> bf16 round-to-nearest-even (finite inputs)
__device__ __forceinline__ ushort f2bf(float x) {
    uint u = __float_as_uint(x);
    u += 0x7fffu + ((u >> 16) & 1u);
    return (ushort)(u >> 16);
}
__device__ __forceinline__ float bf_lo(uint v) { return __uint_as_float(v << 16); }
__device__ __forceinline__ float bf_hi(uint v) { return __uint_as_float(v & 0xffff0000u); }

// ---------------- kernels ----------------

// h0 = concat(x, emb_port[ports], emb_flags[flags]) in bf16; also zeroes bcnt.
__global__ __launch_bounds__(256) void embed_concat_kernel(
    const float* __restrict__ x, const int* __restrict__ ports,
    const int* __restrict__ flags, const float* __restrict__ emb_port,
    const float* __restrict__ emb_flags, ushort* __restrict__ h,
    int* __restrict__ bcnt)
{
    int tid = blockIdx.x * 256 + threadIdx.x;
    if (tid < NBKT) bcnt[tid] = 0;
    int n = tid >> 5, fp = tid & 31;
    if (n >= NN) return;
    int f0 = fp * 2;
    float v0, v1;
    if (f0 < FIN) {
        float2 xv = *(const float2*)(x + (size_t)n * FIN + f0);
        v0 = xv.x; v1 = xv.y;
    } else if (f0 < FIN + 32) {
        float2 pv = *(const float2*)(emb_port + (size_t)ports[n] * 32 + (f0 - FIN));
        v0 = pv.x; v1 = pv.y;
    } else {
        float2 fv = *(const float2*)(emb_flags + (size_t)flags[n] * 2);
        v0 = fv.x; v1 = fv.y;
    }
    uint o = (uint)f2bf(v0) | ((uint)f2bf(v1) << 16);
    ((uint*)h)[n * 32 + fp] = o;
}

// weights f32 -> bf16, original (j,k) orientation: Wb[l][mat][j][k]
__global__ __launch_bounds__(256) void prep_weights_kernel(
    const float* __restrict__ Wrel, const float* __restrict__ Wroot,
    ushort* __restrict__ Wb)
{
    int t = blockIdx.x * 256 + threadIdx.x;
    if (t >= L * 2 * H * H) return;
    int l = t / (2 * H * H), rem = t % (2 * H * H);
    int mat = rem / (H * H), jk = rem % (H * H);
    const float* W = mat ? Wroot : Wrel;
    Wb[t] = f2bf(W[l * H * H + jk]);
}

// pass A: coarse bucket append of (dst, src<<7)
__global__ __launch_bounds__(256) void bucketA_kernel(
    const int* __restrict__ src, const int* __restrict__ dst,
    int* __restrict__ bcnt, int2* __restrict__ tmp)
{
    int e = blockIdx.x * 256 + threadIdx.x;
    if (e >= NE) return;
    int d = dst[e];
    int b = d >> 7;                      // d / BNODES
    int pos = atomicAdd(&bcnt[b], 1);
    if (pos < CAPB) tmp[(size_t)b * CAPB + pos] = make_int2(d, src[e] << 7);
}

// pass B: per-bucket counting sort -> dense per-bucket edge lists + node ranges
__global__ __launch_bounds__(256) void bucketB_kernel(
    const int2* __restrict__ tmp, const int* __restrict__ bcnt,
    int* __restrict__ edge_arr, int2* __restrict__ node_range)
{
    __shared__ int cnt[BNODES];
    __shared__ int off[BNODES];
    __shared__ int cur[BNODES];
    int b = blockIdx.x;
    int tid = threadIdx.x;
    int n0 = b * BNODES;
    int ec = bcnt[b]; if (ec > CAPB) ec = CAPB;
    const int2* te = tmp + (size_t)b * CAPB;

    if (tid < BNODES) cnt[tid] = 0;
    __syncthreads();
    for (int t = tid; t < ec; t += 256) atomicAdd(&cnt[te[t].x & (BNODES - 1)], 1);
    __syncthreads();
    if (tid < 64) {   // wave 0: exclusive scan of 128 counts (2 per lane)
        int v0 = cnt[2 * tid], v1 = cnt[2 * tid + 1];
        int s = v0 + v1;
        for (int o = 1; o < 64; o <<= 1) {
            int t = __shfl_up(s, o);
            if (tid >= o) s += t;
        }
        off[2 * tid]     = s - v1 - v0;
        off[2 * tid + 1] = s - v1;
        cur[2 * tid]     = s - v1 - v0;
        cur[2 * tid + 1] = s - v1;
    }
    __syncthreads();
    for (int t = tid; t < ec; t += 256) {
        int2 e = te[t];
        int p = atomicAdd(&cur[e.x & (BNODES - 1)], 1);
        edge_arr[(size_t)b * CAPB + p] = e.y;
    }
    if (tid < BNODES && n0 + tid < NN)
        node_range[n0 + tid] = make_int2(b * CAPB + off[tid], cnt[tid]);
}

// MFMA GEMMs: z0 = h@Wrel^T (bf16), z1 = h@Wroot^T + brel (bf16).
// Wave = 16 nodes x 64 outputs; A frags loaded straight from global h rows
// (coalesced); B frags from bf16 W[j][k] rows (contiguous per lane).
// D layout (m89): node = (lane>>4)*4 + reg, j = jt*16 + (lane&15).
__global__ __launch_bounds__(256) void gemm_kernel(
    const ushort* __restrict__ h_in, const ushort* __restrict__ Wb,
    const float* __restrict__ brel,
    ushort* __restrict__ z0, ushort* __restrict__ z1)
{
    __shared__ float so[64 * 65];
    int tid = threadIdx.x, lane = tid & 63, w = tid >> 6;
    int m  = lane & 15;
    int kg = lane >> 4;
    int node0 = blockIdx.x * 64 + w * 16;

    int row = node0 + m; if (row >= NN) row = NN - 1;
    const ushort* hr = h_in + (size_t)row * H + kg * 8;
    bf16x8 a0 = *(const bf16x8*)(hr);
    bf16x8 a1 = *(const bf16x8*)(hr + 32);

    f32x4 acc0[4], acc1[4];
#pragma unroll
    for (int jt = 0; jt < 4; ++jt) {
        const ushort* wr0 = Wb + ((size_t)(jt * 16 + m)) * 64 + kg * 8;       // Wrel row
        const ushort* wr1 = wr0 + (size_t)H * H;                              // Wroot row
        bf16x8 b00 = *(const bf16x8*)(wr0);
        bf16x8 b01 = *(const bf16x8*)(wr0 + 32);
        bf16x8 b10 = *(const bf16x8*)(wr1);
        bf16x8 b11 = *(const bf16x8*)(wr1 + 32);
        float bias = brel[jt * 16 + m];
        acc0[jt] = f32x4{0.f, 0.f, 0.f, 0.f};
        acc1[jt] = f32x4{bias, bias, bias, bias};
        acc0[jt] = __builtin_amdgcn_mfma_f32_16x16x32_bf16(a0, b00, acc0[jt], 0, 0, 0);
        acc0[jt] = __builtin_amdgcn_mfma_f32_16x16x32_bf16(a1, b01, acc0[jt], 0, 0, 0);
        acc1[jt] = __builtin_amdgcn_mfma_f32_16x16x32_bf16(a0, b10, acc1[jt], 0, 0, 0);
        acc1[jt] = __builtin_amdgcn_mfma_f32_16x16x32_bf16(a1, b11, acc1[jt], 0, 0, 0);
    }

    int nl = w * 16 + kg * 4;            // node_local base for D regs
    int nodeS0 = blockIdx.x * 64;        // block's first node (store pass)

    // z0 restage + coalesced bf16 store
#pragma unroll
    for (int jt = 0; jt < 4; ++jt)
#pragma unroll
        for (int r = 0; r < 4; ++r)
            so[(nl + r) * 65 + jt * 16 + m] = acc0[jt][r];
    __syncthreads();
    for (int t = tid; t < 512; t += 256) {
        int rr = t >> 3, oct = t & 7;
        if (nodeS0 + rr < NN) {
            const float* s = &so[rr * 65 + oct * 8];
            uint4 v;
            v.x = (uint)f2bf(s[0]) | ((uint)f2bf(s[1]) << 16);
            v.y = (uint)f2bf(s[2]) | ((uint)f2bf(s[3]) << 16);
            v.z = (uint)f2bf(s[4]) | ((uint)f2bf(s[5]) << 16);
            v.w = (uint)f2bf(s[6]) | ((uint)f2bf(s[7]) << 16);
            *((uint4*)(z0 + (size_t)nodeS0 * H) + t) = v;
        }
    }
    __syncthreads();

    // z1 restage + coalesced bf16 store
#pragma unroll
    for (int jt = 0; jt < 4; ++jt)
#pragma unroll
        for (int r = 0; r < 4; ++r)
            so[(nl + r) * 65 + jt * 16 + m] = acc1[jt][r];
    __syncthreads();
    for (int t = tid; t < 512; t += 256) {
        int rr = t >> 3, oct = t & 7;
        if (nodeS0 + rr < NN) {
            const float* s = &so[rr * 65 + oct * 8];
            uint4 v;
            v.x = (uint)f2bf(s[0]) | ((uint)f2bf(s[1]) << 16);
            v.y = (uint)f2bf(s[2]) | ((uint)f2bf(s[3]) << 16);
            v.z = (uint)f2bf(s[4]) | ((uint)f2bf(s[5]) << 16);
            v.w = (uint)f2bf(s[6]) | ((uint)f2bf(s[7]) << 16);
            *((uint4*)(z1 + (size_t)nodeS0 * H) + t) = v;
        }
    }
}

// pure gather: h' = relu( sum_{j->n} z0[j] + z1[n] ).
// No LDS, no barriers; thread = (node n, oct); 4-deep predicated unroll.
__global__ __launch_bounds__(256) void gather_relu_kernel(
    const ushort* __restrict__ z0, const ushort* __restrict__ z1,
    const int2* __restrict__ node_range, const int* __restrict__ edge_arr,
    ushort* __restrict__ h_out)
{
    int tid = blockIdx.x * 256 + threadIdx.x;
    int n = tid >> 3, oct = tid & 7;
    if (n >= NN) return;
    int2 rng = node_range[n];
    int p0 = rng.x, p1 = rng.x + rng.y;
    const char* zb = (const char*)z0 + oct * 16;
    float a[8] = {0.f,0.f,0.f,0.f,0.f,0.f,0.f,0.f};
    for (int p = p0; p < p1; p += 4) {
        int o0 = edge_arr[p];
        bool g1 = (p + 1) < p1, g2 = (p + 2) < p1, g3 = (p + 3) < p1;
        int o1 = g1 ? edge_arr[p + 1] : 0;
        int o2 = g2 ? edge_arr[p + 2] : 0;
        int o3 = g3 ? edge_arr[p + 3] : 0;
        uint4 v0 = *(const uint4*)(zb + o0);
        uint4 v1 = make_uint4(0u,0u,0u,0u);
        uint4 v2 = make_uint4(0u,0u,0u,0u);
        uint4 v3 = make_uint4(0u,0u,0u,0u);
        if (g1) v1 = *(const uint4*)(zb + o1);
        if (g2) v2 = *(const uint4*)(zb + o2);
        if (g3) v3 = *(const uint4*)(zb + o3);
        a[0] += (bf_lo(v0.x) + bf_lo(v1.x)) + (bf_lo(v2.x) + bf_lo(v3.x));
        a[1] += (bf_hi(v0.x) + bf_hi(v1.x)) + (bf_hi(v2.x) + bf_hi(v3.x));
        a[2] += (bf_lo(v0.y) + bf_lo(v1.y)) + (bf_lo(v2.y) + bf_lo(v3.y));
        a[3] += (bf_hi(v0.y) + bf_hi(v1.y)) + (bf_hi(v2.y) + bf_hi(v3.y));
        a[4] += (bf_lo(v0.z) + bf_lo(v1.z)) + (bf_lo(v2.z) + bf_lo(v3.z));
        a[5] += (bf_hi(v0.z) + bf_hi(v1.z)) + (bf_hi(v2.z) + bf_hi(v3.z));
        a[6] += (bf_lo(v0.w) + bf_lo(v1.w)) + (bf_lo(v2.w) + bf_lo(v3.w));
        a[7] += (bf_hi(v0.w) + bf_hi(v1.w)) + (bf_hi(v2.w) + bf_hi(v3.w));
    }
    uint4 sv = *(const uint4*)((const char*)z1 + (size_t)n * 128 + oct * 16);
    a[0] += bf_lo(sv.x); a[1] += bf_hi(sv.x);
    a[2] += bf_lo(sv.y); a[3] += bf_hi(sv.y);
    a[4] += bf_lo(sv.z); a[5] += bf_hi(sv.z);
    a[6] += bf_lo(sv.w); a[7] += bf_hi(sv.w);
    uint4 o;
    o.x = (uint)f2bf(fmaxf(a[0], 0.f)) | ((uint)f2bf(fmaxf(a[1], 0.f)) << 16);
    o.y = (uint)f2bf(fmaxf(a[2], 0.f)) | ((uint)f2bf(fmaxf(a[3], 0.f)) << 16);
    o.z = (uint)f2bf(fmaxf(a[4], 0.f)) | ((uint)f2bf(fmaxf(a[5], 0.f)) << 16);
    o.w = (uint)f2bf(fmaxf(a[6], 0.f)) | ((uint)f2bf(fmaxf(a[7], 0.f)) << 16);
    *((uint4*)h_out + tid) = o;
}

// fused max-pool + MLP head: one block per graph
__global__ __launch_bounds__(256) void pool_mlp_kernel(
    const ushort* __restrict__ h, const int* __restrict__ batch,
    const float* __restrict__ fc1W, const float* __restrict__ fc1b,
    const float* __restrict__ fc2W, const float* __restrict__ fc2b,
    const float* __restrict__ fc3W, const float* __restrict__ fc3b,
    float* __restrict__ out)
{
    __shared__ float red[4][64];
    __shared__ float s0[64];
    __shared__ float s1[64];
    __shared__ float s2[64];
    int b = blockIdx.x;
    int tid = threadIdx.x;
    int f = tid & 63, w = tid >> 6;
    int lo = 0, hi = NN;
    while (lo < hi) { int mid = (lo + hi) >> 1; if (batch[mid] < b) lo = mid + 1; else hi = mid; }
    int lo2 = lo, hi2 = NN;
    while (lo2 < hi2) { int mid = (lo2 + hi2) >> 1; if (batch[mid] < b + 1) lo2 = mid + 1; else hi2 = mid; }
    float m = -3.402823466e38f;
    for (int n = lo + w; n < lo2; n += 4) {
        ushort u = h[(size_t)n * H + f];
        m = fmaxf(m, __uint_as_float((uint)u << 16));
    }
    red[w][f] = m;
    __syncthreads();
    int j = tid;
    if (tid < 64)
        s0[j] = fmaxf(fmaxf(red[0][j], red[1][j]), fmaxf(red[2][j], red[3][j]));
    __syncthreads();
    float acc = 0.f;
    if (tid < 64) {
        acc = fc1b[j];
        for (int k = 0; k < 64; ++k) acc = fmaf(s0[k], fc1W[j * 64 + k], acc);
    }
    __syncthreads();
    if (tid < 64) s1[j] = fmaxf(acc, 0.f);
    __syncthreads();
    if (tid < 64) {
        acc = fc2b[j];
        for (int k = 0; k < 64; ++k) acc = fmaf(s1[k], fc2W[j * 64 + k], acc);
    }
    __syncthreads();
    if (tid < 64) s2[j] = fmaxf(acc, 0.f);
    __syncthreads();
    if (tid < NC) {
        acc = fc3b[j];
        for (int k = 0; k < 64; ++k) acc = fmaf(s2[k], fc3W[j * 64 + k], acc);
        out[b * NC + j] = acc;
    }
}

// ---------------- launcher ----------------

extern "C" void kernel_launch(void* const* d_in, const int* in_sizes, int n_in,
                              void* d_out, int out_size, void* d_ws, size_t ws_size,
                              hipStream_t stream)
{
    const float* x         = (const float*)d_in[0];
    const int*   dst_ports = (const int*)d_in[1];
    const int*   tcp_flags = (const int*)d_in[2];
    const int*   edge_src_in = (const int*)d_in[3];          // row 0 of (2,E)
    const int*   edge_dst_in = edge_src_in + NE;             // row 1
    const int*   batch     = (const int*)d_in[4];
    const float* emb_port  = (const float*)d_in[5];
    const float* emb_flags = (const float*)d_in[6];
    const float* Wrel      = (const float*)d_in[7];
    const float* brel      = (const float*)d_in[8];
    const float* Wroot     = (const float*)d_in[9];
    const float* fc1W      = (const float*)d_in[10];
    const float* fc1b      = (const float*)d_in[11];
    const float* fc2W      = (const float*)d_in[12];
    const float* fc2b      = (const float*)d_in[13];
    const float* fc3W      = (const float*)d_in[14];
    const float* fc3b      = (const float*)d_in[15];
    float* out = (float*)d_out;

    // workspace carve-up (256B aligned)
    char* ws = (char*)d_ws;
    size_t off = 0;
    auto alloc = [&](size_t bytes) {
        void* p = ws + off;
        off += (bytes + 255) & ~(size_t)255;
        return p;
    };
    ushort* h0        = (ushort*)alloc((size_t)NN * H * 2);
    ushort* h1        = (ushort*)alloc((size_t)NN * H * 2);
    ushort* z0        = (ushort*)alloc((size_t)NN * H * 2);
    ushort* z1        = (ushort*)alloc((size_t)NN * H * 2);
    int2*   tmp       = (int2*)alloc((size_t)NBKT * CAPB * 8);
    int*    edge_arr  = (int*)alloc((size_t)NBKT * CAPB * 4);
    int2*   node_range= (int2*)alloc((size_t)NN * 8);
    int*    bcnt      = (int*)alloc((size_t)NBKT * 4);
    ushort* Wb        = (ushort*)alloc((size_t)L * 2 * H * H * 2);

    // h0 = concat(...) in bf16; also zeroes bcnt (before bucketA)
    embed_concat_kernel<<<(NN * 32 + 255) / 256, 256, 0, stream>>>(
        x, dst_ports, tcp_flags, emb_port, emb_flags, h0, bcnt);

    // weight conversion (tiny)
    prep_weights_kernel<<<(L * 2 * H * H + 255) / 256, 256, 0, stream>>>(Wrel, Wroot, Wb);

    // CSR via two-pass bucket counting sort
    bucketA_kernel<<<(NE + 255) / 256, 256, 0, stream>>>(edge_src_in, edge_dst_in, bcnt, tmp);
    bucketB_kernel<<<NBKT, 256, 0, stream>>>(tmp, bcnt, edge_arr, node_range);

    // 3 layers: MFMA GEMMs then pure gather; ping-pong h0<->h1
    const int ggrid = (NN + 63) / 64;
    const int agrid = (NN * 8 + 255) / 256;
    ushort* hin = h0; ushort* hout = h1;
    for (int l = 0; l < L; ++l) {
        gemm_kernel<<<ggrid, 256, 0, stream>>>(
            hin, Wb + (size_t)l * 2 * H * H, brel + (size_t)l * H, z0, z1);
        gather_relu_kernel<<<agrid, 256, 0, stream>>>(z0, z1, node_range, edge_arr, hout);
        ushort* tmpp = hin; hin = hout; hout = tmpp;
    }

    // fused global max pool + MLP head (final h is hin after swap)
    pool_mlp_kernel<<<NB, 256, 0, stream>>>(
        hin, batch, fc1W, fc1b, fc2W, fc2b, fc3W, fc3b, out);
}

// Round 10
// 307.505 us; speedup vs baseline: 1.6776x; 1.6776x over previous
//
#include <hip/hip_runtime.h>

#define NN 50000
#define NE 800000
#define NB 128
#define FIN 30
#define H 64
#define NC 10
#define L 3

typedef unsigned int uint;
typedef unsigned short ushort;
typedef __attribute__((ext_vector_type(8))) short bf16x8;
typedef __attribute__((ext_vector_type(4))) float f32x4;

// f32 -> bf16 round-to-nearest-even (finite inputs)
__device__ __forceinline__ ushort f2bf(float x) {
    uint u = __float_as_uint(x);
    u += 0x7fffu + ((u >> 16) & 1u);
    return (ushort)(u >> 16);
}
__device__ __forceinline__ float bf_lo(uint v) { return __uint_as_float(v << 16); }
__device__ __forceinline__ float bf_hi(uint v) { return __uint_as_float(v & 0xffff0000u); }

// ---------------- kernels ----------------

// h0 = concat(x, emb_port[ports], emb_flags[flags]) in bf16; also zeroes cnt.
__global__ __launch_bounds__(256) void embed_concat_kernel(
    const float* __restrict__ x, const int* __restrict__ ports,
    const int* __restrict__ flags, const float* __restrict__ emb_port,
    const float* __restrict__ emb_flags, ushort* __restrict__ h,
    int* __restrict__ cnt)
{
    int tid = blockIdx.x * 256 + threadIdx.x;
    int n = tid >> 5, fp = tid & 31;
    if (n >= NN) return;
    if (fp == 0) cnt[n] = 0;
    int f0 = fp * 2;
    float v0, v1;
    if (f0 < FIN) {
        float2 xv = *(const float2*)(x + (size_t)n * FIN + f0);
        v0 = xv.x; v1 = xv.y;
    } else if (f0 < FIN + 32) {
        float2 pv = *(const float2*)(emb_port + (size_t)ports[n] * 32 + (f0 - FIN));
        v0 = pv.x; v1 = pv.y;
    } else {
        float2 fv = *(const float2*)(emb_flags + (size_t)flags[n] * 2);
        v0 = fv.x; v1 = fv.y;
    }
    uint o = (uint)f2bf(v0) | ((uint)f2bf(v1) << 16);
    ((uint*)h)[n * 32 + fp] = o;
}

// weights f32 -> bf16, original (j,k) orientation: Wb[l][mat][j][k]
__global__ __launch_bounds__(256) void prep_weights_kernel(
    const float* __restrict__ Wrel, const float* __restrict__ Wroot,
    ushort* __restrict__ Wb)
{
    int t = blockIdx.x * 256 + threadIdx.x;
    if (t >= L * 2 * H * H) return;
    int l = t / (2 * H * H), rem = t % (2 * H * H);
    int mat = rem / (H * H), jk = rem % (H * H);
    const float* W = mat ? Wroot : Wrel;
    Wb[t] = f2bf(W[l * H * H + jk]);
}

__global__ __launch_bounds__(256) void hist_kernel(
    const int* __restrict__ dst, int* __restrict__ cnt)
{
    int e = blockIdx.x * 256 + threadIdx.x;
    if (e < NE) atomicAdd(&cnt[dst[e]], 1);
}

// ---- hierarchical scan; also zeroes cursor (used later by scatter) ----

__global__ __launch_bounds__(1024) void scan1_kernel(
    const int* __restrict__ cnt, int* __restrict__ row_start,
    int* __restrict__ bsum, int* __restrict__ cursor)
{
    __shared__ int wsum[16];
    int i = blockIdx.x * 1024 + threadIdx.x;
    int lane = threadIdx.x & 63;
    int wv = threadIdx.x >> 6;
    if (i < NN) cursor[i] = 0;
    int v = (i < NN) ? cnt[i] : 0;
    int s = v;
    for (int off = 1; off < 64; off <<= 1) {
        int t = __shfl_up(s, off);
        if (lane >= off) s += t;
    }
    if (lane == 63) wsum[wv] = s;
    __syncthreads();
    if (wv == 0) {
        int ws = (lane < 16) ? wsum[lane] : 0;
        for (int off = 1; off < 16; off <<= 1) {
            int t = __shfl_up(ws, off);
            if (lane >= off) ws += t;
        }
        if (lane < 16) wsum[lane] = ws;
    }
    __syncthreads();
    int base = (wv > 0) ? wsum[wv - 1] : 0;
    s += base;
    if (i < NN) row_start[i + 1] = s;
    if (threadIdx.x == 1023) bsum[blockIdx.x] = s;
    if (i == 0) row_start[0] = 0;
}

__global__ __launch_bounds__(64) void scan2_kernel(int* __restrict__ bsum)
{
    int lane = threadIdx.x;
    int v = (lane < 49) ? bsum[lane] : 0;
    for (int off = 1; off < 64; off <<= 1) {
        int t = __shfl_up(v, off);
        if (lane >= off) v += t;
    }
    if (lane < 49) bsum[lane] = v;
}

__global__ __launch_bounds__(1024) void scan3_kernel(
    int* __restrict__ row_start, const int* __restrict__ bsum)
{
    int b = blockIdx.x + 1;
    int i = b * 1024 + threadIdx.x;
    if (i < NN) row_start[i + 1] += bsum[b - 1];
}

// CSR bucket fill; stores BYTE offsets (src * 128). Index guard keeps rocprof
// counter-replay (re-runs without re-zeroed cursor) in bounds.
__global__ __launch_bounds__(256) void scatter_edges_kernel(
    const int* __restrict__ src, const int* __restrict__ dst,
    const int* __restrict__ row_start, int* __restrict__ cursor,
    int* __restrict__ edge_src)
{
    int e = blockIdx.x * 256 + threadIdx.x;
    if (e >= NE) return;
    int d = dst[e];
    int pos = atomicAdd(&cursor[d], 1);
    int idx = row_start[d] + pos;
    if (idx < NE) edge_src[idx] = src[e] << 7;
}

// MFMA GEMMs: z0 = h@Wrel^T (bf16), z1 = h@Wroot^T + brel (bf16).
// Wave = 16 nodes x 64 outputs; A frags loaded straight from global h rows
// (coalesced); B frags from bf16 W[j][k] rows (contiguous per lane).
// D layout (m89): node = (lane>>4)*4 + reg, j = jt*16 + (lane&15).
__global__ __launch_bounds__(256) void gemm_kernel(
    const ushort* __restrict__ h_in, const ushort* __restrict__ Wb,
    const float* __restrict__ brel,
    ushort* __restrict__ z0, ushort* __restrict__ z1)
{
    __shared__ float so[64 * 65];
    int tid = threadIdx.x, lane = tid & 63, w = tid >> 6;
    int m  = lane & 15;
    int kg = lane >> 4;
    int node0 = blockIdx.x * 64 + w * 16;

    int row = node0 + m; if (row >= NN) row = NN - 1;
    const ushort* hr = h_in + (size_t)row * H + kg * 8;
    bf16x8 a0 = *(const bf16x8*)(hr);
    bf16x8 a1 = *(const bf16x8*)(hr + 32);

    f32x4 acc0[4], acc1[4];
#pragma unroll
    for (int jt = 0; jt < 4; ++jt) {
        const ushort* wr0 = Wb + ((size_t)(jt * 16 + m)) * 64 + kg * 8;       // Wrel row
        const ushort* wr1 = wr0 + (size_t)H * H;                              // Wroot row
        bf16x8 b00 = *(const bf16x8*)(wr0);
        bf16x8 b01 = *(const bf16x8*)(wr0 + 32);
        bf16x8 b10 = *(const bf16x8*)(wr1);
        bf16x8 b11 = *(const bf16x8*)(wr1 + 32);
        float bias = brel[jt * 16 + m];
        acc0[jt] = f32x4{0.f, 0.f, 0.f, 0.f};
        acc1[jt] = f32x4{bias, bias, bias, bias};
        acc0[jt] = __builtin_amdgcn_mfma_f32_16x16x32_bf16(a0, b00, acc0[jt], 0, 0, 0);
        acc0[jt] = __builtin_amdgcn_mfma_f32_16x16x32_bf16(a1, b01, acc0[jt], 0, 0, 0);
        acc1[jt] = __builtin_amdgcn_mfma_f32_16x16x32_bf16(a0, b10, acc1[jt], 0, 0, 0);
        acc1[jt] = __builtin_amdgcn_mfma_f32_16x16x32_bf16(a1, b11, acc1[jt], 0, 0, 0);
    }

    int nl = w * 16 + kg * 4;            // node_local base for D regs
    int nodeS0 = blockIdx.x * 64;        // block's first node (store pass)

    // z0 restage + coalesced bf16 store
#pragma unroll
    for (int jt = 0; jt < 4; ++jt)
#pragma unroll
        for (int r = 0; r < 4; ++r)
            so[(nl + r) * 65 + jt * 16 + m] = acc0[jt][r];
    __syncthreads();
    for (int t = tid; t < 512; t += 256) {
        int rr = t >> 3, oct = t & 7;
        if (nodeS0 + rr < NN) {
            const float* s = &so[rr * 65 + oct * 8];
            uint4 v;
            v.x = (uint)f2bf(s[0]) | ((uint)f2bf(s[1]) << 16);
            v.y = (uint)f2bf(s[2]) | ((uint)f2bf(s[3]) << 16);
            v.z = (uint)f2bf(s[4]) | ((uint)f2bf(s[5]) << 16);
            v.w = (uint)f2bf(s[6]) | ((uint)f2bf(s[7]) << 16);
            *((uint4*)(z0 + (size_t)nodeS0 * H) + t) = v;
        }
    }
    __syncthreads();

    // z1 restage + coalesced bf16 store
#pragma unroll
    for (int jt = 0; jt < 4; ++jt)
#pragma unroll
        for (int r = 0; r < 4; ++r)
            so[(nl + r) * 65 + jt * 16 + m] = acc1[jt][r];
    __syncthreads();
    for (int t = tid; t < 512; t += 256) {
        int rr = t >> 3, oct = t & 7;
        if (nodeS0 + rr < NN) {
            const float* s = &so[rr * 65 + oct * 8];
            uint4 v;
            v.x = (uint)f2bf(s[0]) | ((uint)f2bf(s[1]) << 16);
            v.y = (uint)f2bf(s[2]) | ((uint)f2bf(s[3]) << 16);
            v.z = (uint)f2bf(s[4]) | ((uint)f2bf(s[5]) << 16);
            v.w = (uint)f2bf(s[6]) | ((uint)f2bf(s[7]) << 16);
            *((uint4*)(z1 + (size_t)nodeS0 * H) + t) = v;
        }
    }
}

// pure gather: h' = relu( sum_{j->n} z0[j] + z1[n] ).
// No LDS, no barriers; thread = (node n, oct); 4-deep predicated unroll.
__global__ __launch_bounds__(256) void gather_relu_kernel(
    const ushort* __restrict__ z0, const ushort* __restrict__ z1,
    const int* __restrict__ row_start, const int* __restrict__ edge_src,
    ushort* __restrict__ h_out)
{
    int tid = blockIdx.x * 256 + threadIdx.x;
    int n = tid >> 3, oct = tid & 7;
    if (n >= NN) return;
    int p0 = row_start[n], p1 = row_start[n + 1];
    const char* zb = (const char*)z0 + oct * 16;
    float a[8] = {0.f,0.f,0.f,0.f,0.f,0.f,0.f,0.f};
    for (int p = p0; p < p1; p += 4) {
        int o0 = edge_src[p];
        bool g1 = (p + 1) < p1, g2 = (p + 2) < p1, g3 = (p + 3) < p1;
        int o1 = g1 ? edge_src[p + 1] : 0;
        int o2 = g2 ? edge_src[p + 2] : 0;
        int o3 = g3 ? edge_src[p + 3] : 0;
        uint4 v0 = *(const uint4*)(zb + o0);
        uint4 v1 = make_uint4(0u,0u,0u,0u);
        uint4 v2 = make_uint4(0u,0u,0u,0u);
        uint4 v3 = make_uint4(0u,0u,0u,0u);
        if (g1) v1 = *(const uint4*)(zb + o1);
        if (g2) v2 = *(const uint4*)(zb + o2);
        if (g3) v3 = *(const uint4*)(zb + o3);
        a[0] += (bf_lo(v0.x) + bf_lo(v1.x)) + (bf_lo(v2.x) + bf_lo(v3.x));
        a[1] += (bf_hi(v0.x) + bf_hi(v1.x)) + (bf_hi(v2.x) + bf_hi(v3.x));
        a[2] += (bf_lo(v0.y) + bf_lo(v1.y)) + (bf_lo(v2.y) + bf_lo(v3.y));
        a[3] += (bf_hi(v0.y) + bf_hi(v1.y)) + (bf_hi(v2.y) + bf_hi(v3.y));
        a[4] += (bf_lo(v0.z) + bf_lo(v1.z)) + (bf_lo(v2.z) + bf_lo(v3.z));
        a[5] += (bf_hi(v0.z) + bf_hi(v1.z)) + (bf_hi(v2.z) + bf_hi(v3.z));
        a[6] += (bf_lo(v0.w) + bf_lo(v1.w)) + (bf_lo(v2.w) + bf_lo(v3.w));
        a[7] += (bf_hi(v0.w) + bf_hi(v1.w)) + (bf_hi(v2.w) + bf_hi(v3.w));
    }
    uint4 sv = *(const uint4*)((const char*)z1 + (size_t)n * 128 + oct * 16);
    a[0] += bf_lo(sv.x); a[1] += bf_hi(sv.x);
    a[2] += bf_lo(sv.y); a[3] += bf_hi(sv.y);
    a[4] += bf_lo(sv.z); a[5] += bf_hi(sv.z);
    a[6] += bf_lo(sv.w); a[7] += bf_hi(sv.w);
    uint4 o;
    o.x = (uint)f2bf(fmaxf(a[0], 0.f)) | ((uint)f2bf(fmaxf(a[1], 0.f)) << 16);
    o.y = (uint)f2bf(fmaxf(a[2], 0.f)) | ((uint)f2bf(fmaxf(a[3], 0.f)) << 16);
    o.z = (uint)f2bf(fmaxf(a[4], 0.f)) | ((uint)f2bf(fmaxf(a[5], 0.f)) << 16);
    o.w = (uint)f2bf(fmaxf(a[6], 0.f)) | ((uint)f2bf(fmaxf(a[7], 0.f)) << 16);
    *((uint4*)h_out + tid) = o;
}

// fused max-pool + MLP head: one block per graph
__global__ __launch_bounds__(256) void pool_mlp_kernel(
    const ushort* __restrict__ h, const int* __restrict__ batch,
    const float* __restrict__ fc1W, const float* __restrict__ fc1b,
    const float* __restrict__ fc2W, const float* __restrict__ fc2b,
    const float* __restrict__ fc3W, const float* __restrict__ fc3b,
    float* __restrict__ out)
{
    __shared__ float red[4][64];
    __shared__ float s0[64];
    __shared__ float s1[64];
    __shared__ float s2[64];
    int b = blockIdx.x;
    int tid = threadIdx.x;
    int f = tid & 63, w = tid >> 6;
    int lo = 0, hi = NN;
    while (lo < hi) { int mid = (lo + hi) >> 1; if (batch[mid] < b) lo = mid + 1; else hi = mid; }
    int lo2 = lo, hi2 = NN;
    while (lo2 < hi2) { int mid = (lo2 + hi2) >> 1; if (batch[mid] < b + 1) lo2 = mid + 1; else hi2 = mid; }
    float m = -3.402823466e38f;
    for (int n = lo + w; n < lo2; n += 4) {
        ushort u = h[(size_t)n * H + f];
        m = fmaxf(m, __uint_as_float((uint)u << 16));
    }
    red[w][f] = m;
    __syncthreads();
    int j = tid;
    if (tid < 64)
        s0[j] = fmaxf(fmaxf(red[0][j], red[1][j]), fmaxf(red[2][j], red[3][j]));
    __syncthreads();
    float acc = 0.f;
    if (tid < 64) {
        acc = fc1b[j];
        for (int k = 0; k < 64; ++k) acc = fmaf(s0[k], fc1W[j * 64 + k], acc);
    }
    __syncthreads();
    if (tid < 64) s1[j] = fmaxf(acc, 0.f);
    __syncthreads();
    if (tid < 64) {
        acc = fc2b[j];
        for (int k = 0; k < 64; ++k) acc = fmaf(s1[k], fc2W[j * 64 + k], acc);
    }
    __syncthreads();
    if (tid < 64) s2[j] = fmaxf(acc, 0.f);
    __syncthreads();
    if (tid < NC) {
        acc = fc3b[j];
        for (int k = 0; k < 64; ++k) acc = fmaf(s2[k], fc3W[j * 64 + k], acc);
        out[b * NC + j] = acc;
    }
}

// ---------------- launcher ----------------

extern "C" void kernel_launch(void* const* d_in, const int* in_sizes, int n_in,
                              void* d_out, int out_size, void* d_ws, size_t ws_size,
                              hipStream_t stream)
{
    const float* x         = (const float*)d_in[0];
    const int*   dst_ports = (const int*)d_in[1];
    const int*   tcp_flags = (const int*)d_in[2];
    const int*   edge_src_in = (const int*)d_in[3];          // row 0 of (2,E)
    const int*   edge_dst_in = edge_src_in + NE;             // row 1
    const int*   batch     = (const int*)d_in[4];
    const float* emb_port  = (const float*)d_in[5];
    const float* emb_flags = (const float*)d_in[6];
    const float* Wrel      = (const float*)d_in[7];
    const float* brel      = (const float*)d_in[8];
    const float* Wroot     = (const float*)d_in[9];
    const float* fc1W      = (const float*)d_in[10];
    const float* fc1b      = (const float*)d_in[11];
    const float* fc2W      = (const float*)d_in[12];
    const float* fc2b      = (const float*)d_in[13];
    const float* fc3W      = (const float*)d_in[14];
    const float* fc3b      = (const float*)d_in[15];
    float* out = (float*)d_out;

    // workspace carve-up (256B aligned)
    char* ws = (char*)d_ws;
    size_t off = 0;
    auto alloc = [&](size_t bytes) {
        void* p = ws + off;
        off += (bytes + 255) & ~(size_t)255;
        return p;
    };
    ushort* h0      = (ushort*)alloc((size_t)NN * H * 2);
    ushort* h1      = (ushort*)alloc((size_t)NN * H * 2);
    ushort* z0      = (ushort*)alloc((size_t)NN * H * 2);
    ushort* z1      = (ushort*)alloc((size_t)NN * H * 2);
    int*   cnt      = (int*)alloc((size_t)NN * 4);
    int*   row_start= (int*)alloc((size_t)(NN + 1) * 4);
    int*   cursor   = (int*)alloc((size_t)NN * 4);
    int*   edge_src = (int*)alloc((size_t)NE * 4);
    int*   bsum     = (int*)alloc((size_t)64 * 4);
    ushort* Wb      = (ushort*)alloc((size_t)L * 2 * H * H * 2);

    // h0 = concat(...) in bf16; also zeroes cnt (before hist)
    embed_concat_kernel<<<(NN * 32 + 255) / 256, 256, 0, stream>>>(
        x, dst_ports, tcp_flags, emb_port, emb_flags, h0, cnt);

    // weight conversion (tiny)
    prep_weights_kernel<<<(L * 2 * H * H + 255) / 256, 256, 0, stream>>>(Wrel, Wroot, Wb);

    // CSR build (by dst): hist over 50k counters (low contention) + scan + scatter
    hist_kernel<<<(NE + 255) / 256, 256, 0, stream>>>(edge_dst_in, cnt);
    scan1_kernel<<<(NN + 1023) / 1024, 1024, 0, stream>>>(cnt, row_start, bsum, cursor);
    scan2_kernel<<<1, 64, 0, stream>>>(bsum);
    scan3_kernel<<<(NN + 1023) / 1024 - 1, 1024, 0, stream>>>(row_start, bsum);
    scatter_edges_kernel<<<(NE + 255) / 256, 256, 0, stream>>>(
        edge_src_in, edge_dst_in, row_start, cursor, edge_src);

    // 3 layers: MFMA GEMMs then pure gather; ping-pong h0<->h1
    const int ggrid = (NN + 63) / 64;
    const int agrid = (NN * 8 + 255) / 256;
    ushort* hin = h0; ushort* hout = h1;
    for (int l = 0; l < L; ++l) {
        gemm_kernel<<<ggrid, 256, 0, stream>>>(
            hin, Wb + (size_t)l * 2 * H * H, brel + (size_t)l * H, z0, z1);
        gather_relu_kernel<<<agrid, 256, 0, stream>>>(z0, z1, row_start, edge_src, hout);
        ushort* tmpp = hin; hin = hout; hout = tmpp;
    }

    // fused global max pool + MLP head (final h is hin after swap)
    pool_mlp_kernel<<<NB, 256, 0, stream>>>(
        hin, batch, fc1W, fc1b, fc2W, fc2b, fc3W, fc3b, out);
}

// Round 11
// 292.326 us; speedup vs baseline: 1.7648x; 1.0519x over previous
//
#include <hip/hip_runtime.h>

#define NN 50000
#define NE 800000
#define NB 128
#define FIN 30
#define H 64
#define NC 10
#define L 3

#define BKN 4                 // nodes per bucket
#define NBK 12500             // NN / BKN (exact)
#define BKCAP 128             // edge capacity per bucket (lambda=64, +8 sigma)
#define BSTRIDE 16            // bcnt padding: one counter per 64B line

typedef unsigned int uint;
typedef unsigned short ushort;
typedef __attribute__((ext_vector_type(8))) short bf16x8;
typedef __attribute__((ext_vector_type(4))) float f32x4;

// f32 -> bf16 round-to-nearest-even (finite inputs)
__device__ __forceinline__ ushort f2bf(float x) {
    uint u = __float_as_uint(x);
    u += 0x7fffu + ((u >> 16) & 1u);
    return (ushort)(u >> 16);
}
__device__ __forceinline__ float bf_lo(uint v) { return __uint_as_float(v << 16); }
__device__ __forceinline__ float bf_hi(uint v) { return __uint_as_float(v & 0xffff0000u); }

// ---------------- kernels ----------------

// weights f32 -> bf16 (Wb[l][mat][j][k]); also zeroes padded bucket counters.
__global__ __launch_bounds__(256) void prep_weights_kernel(
    const float* __restrict__ Wrel, const float* __restrict__ Wroot,
    ushort* __restrict__ Wb, int* __restrict__ bcnt)
{
    int t = blockIdx.x * 256 + threadIdx.x;
    for (int i = t; i < NBK * BSTRIDE; i += 96 * 256) bcnt[i] = 0;
    if (t >= L * 2 * H * H) return;
    int l = t / (2 * H * H), rem = t % (2 * H * H);
    int mat = rem / (H * H), jk = rem % (H * H);
    const float* W = mat ? Wroot : Wrel;
    Wb[t] = f2bf(W[l * H * H + jk]);
}

// pass A: append (node-in-bucket, src byte-offset) into coarse buckets.
// Counters padded to 64B lines; tail chain ~100 x 138ns ~= 14us.
__global__ __launch_bounds__(256) void bucketA_kernel(
    const int* __restrict__ src, const int* __restrict__ dst,
    int* __restrict__ bcnt, int2* __restrict__ tmp)
{
    int e = blockIdx.x * 256 + threadIdx.x;
    if (e >= NE) return;
    int d = dst[e];
    int b = d >> 2;
    int pos = atomicAdd(&bcnt[b * BSTRIDE], 1);
    if (pos < BKCAP) tmp[(size_t)b * BKCAP + pos] = make_int2(d & 3, src[e] << 7);
}

// pass B: per-bucket counting sort (4 nodes) -> dense edge lists + node ranges
__global__ __launch_bounds__(64) void bucketB_kernel(
    const int2* __restrict__ tmp, const int* __restrict__ bcnt,
    int* __restrict__ edge_arr, int2* __restrict__ node_range)
{
    __shared__ int cnt[BKN];
    __shared__ int off[BKN];
    __shared__ int cur[BKN];
    int b = blockIdx.x;
    int tid = threadIdx.x;
    int ec = bcnt[b * BSTRIDE]; if (ec > BKCAP) ec = BKCAP;
    const int2* te = tmp + (size_t)b * BKCAP;

    if (tid < BKN) cnt[tid] = 0;
    __syncthreads();
    for (int t = tid; t < ec; t += 64) atomicAdd(&cnt[te[t].x], 1);
    __syncthreads();
    if (tid == 0) {
        int s = 0;
#pragma unroll
        for (int i = 0; i < BKN; ++i) { off[i] = s; cur[i] = s; s += cnt[i]; }
    }
    __syncthreads();
    for (int t = tid; t < ec; t += 64) {
        int2 ed = te[t];
        int p = atomicAdd(&cur[ed.x], 1);
        edge_arr[(size_t)b * BKCAP + p] = ed.y;
    }
    if (tid < BKN) {
        int n = b * BKN + tid;
        if (n < NN) node_range[n] = make_int2(b * BKCAP + off[tid], cnt[tid]);
    }
}

// fused embed + MFMA GEMM for layer 0: stages concat(x, emb_port, emb_flags)
// into LDS (f32), builds A fragments, computes z0 = h@Wrel^T, z1 = h@Wroot^T+brel.
__global__ __launch_bounds__(256) void gemm0_fused_kernel(
    const float* __restrict__ x, const int* __restrict__ ports,
    const int* __restrict__ flags, const float* __restrict__ emb_port,
    const float* __restrict__ emb_flags,
    const ushort* __restrict__ Wb, const float* __restrict__ brel,
    ushort* __restrict__ z0, ushort* __restrict__ z1)
{
    __shared__ float sf[64 * 65];   // staged input rows (f32)
    __shared__ float so[64 * 65];   // output restage
    int tid = threadIdx.x, lane = tid & 63, w = tid >> 6;
    int node0 = blockIdx.x * 64;

    // stage concat rows: wave w covers row w (+4 per step), lanes = features
    for (int t = tid; t < 4096; t += 256) {
        int r = t >> 6, f = t & 63;
        int n = node0 + r;
        float v = 0.f;
        if (n < NN) {
            if (f < FIN)       v = x[(size_t)n * FIN + f];
            else if (f < 62)   v = emb_port[(size_t)ports[n] * 32 + (f - FIN)];
            else               v = emb_flags[(size_t)flags[n] * 2 + (f - 62)];
        }
        sf[r * 65 + f] = v;
    }
    __syncthreads();

    int m  = lane & 15;
    int kg = lane >> 4;
    int rloc = w * 16 + m;
    const float* fr = &sf[rloc * 65 + kg * 8];
    bf16x8 a0, a1;
#pragma unroll
    for (int i = 0; i < 8; ++i) {
        a0[i] = (short)f2bf(fr[i]);
        a1[i] = (short)f2bf(fr[32 + i]);
    }

    f32x4 acc0[4], acc1[4];
#pragma unroll
    for (int jt = 0; jt < 4; ++jt) {
        const ushort* wr0 = Wb + ((size_t)(jt * 16 + m)) * 64 + kg * 8;
        const ushort* wr1 = wr0 + (size_t)H * H;
        bf16x8 b00 = *(const bf16x8*)(wr0);
        bf16x8 b01 = *(const bf16x8*)(wr0 + 32);
        bf16x8 b10 = *(const bf16x8*)(wr1);
        bf16x8 b11 = *(const bf16x8*)(wr1 + 32);
        float bias = brel[jt * 16 + m];
        acc0[jt] = f32x4{0.f, 0.f, 0.f, 0.f};
        acc1[jt] = f32x4{bias, bias, bias, bias};
        acc0[jt] = __builtin_amdgcn_mfma_f32_16x16x32_bf16(a0, b00, acc0[jt], 0, 0, 0);
        acc0[jt] = __builtin_amdgcn_mfma_f32_16x16x32_bf16(a1, b01, acc0[jt], 0, 0, 0);
        acc1[jt] = __builtin_amdgcn_mfma_f32_16x16x32_bf16(a0, b10, acc1[jt], 0, 0, 0);
        acc1[jt] = __builtin_amdgcn_mfma_f32_16x16x32_bf16(a1, b11, acc1[jt], 0, 0, 0);
    }

    int nl = w * 16 + kg * 4;

    // z0 restage + coalesced bf16 store
#pragma unroll
    for (int jt = 0; jt < 4; ++jt)
#pragma unroll
        for (int r = 0; r < 4; ++r)
            so[(nl + r) * 65 + jt * 16 + m] = acc0[jt][r];
    __syncthreads();
    for (int t = tid; t < 512; t += 256) {
        int rr = t >> 3, oct = t & 7;
        if (node0 + rr < NN) {
            const float* s = &so[rr * 65 + oct * 8];
            uint4 v;
            v.x = (uint)f2bf(s[0]) | ((uint)f2bf(s[1]) << 16);
            v.y = (uint)f2bf(s[2]) | ((uint)f2bf(s[3]) << 16);
            v.z = (uint)f2bf(s[4]) | ((uint)f2bf(s[5]) << 16);
            v.w = (uint)f2bf(s[6]) | ((uint)f2bf(s[7]) << 16);
            *((uint4*)(z0 + (size_t)node0 * H) + t) = v;
        }
    }
    __syncthreads();

    // z1 restage + coalesced bf16 store
#pragma unroll
    for (int jt = 0; jt < 4; ++jt)
#pragma unroll
        for (int r = 0; r < 4; ++r)
            so[(nl + r) * 65 + jt * 16 + m] = acc1[jt][r];
    __syncthreads();
    for (int t = tid; t < 512; t += 256) {
        int rr = t >> 3, oct = t & 7;
        if (node0 + rr < NN) {
            const float* s = &so[rr * 65 + oct * 8];
            uint4 v;
            v.x = (uint)f2bf(s[0]) | ((uint)f2bf(s[1]) << 16);
            v.y = (uint)f2bf(s[2]) | ((uint)f2bf(s[3]) << 16);
            v.z = (uint)f2bf(s[4]) | ((uint)f2bf(s[5]) << 16);
            v.w = (uint)f2bf(s[6]) | ((uint)f2bf(s[7]) << 16);
            *((uint4*)(z1 + (size_t)node0 * H) + t) = v;
        }
    }
}

// MFMA GEMMs (layers 1,2): z0 = h@Wrel^T, z1 = h@Wroot^T + brel (bf16 in/out).
__global__ __launch_bounds__(256) void gemm_kernel(
    const ushort* __restrict__ h_in, const ushort* __restrict__ Wb,
    const float* __restrict__ brel,
    ushort* __restrict__ z0, ushort* __restrict__ z1)
{
    __shared__ float so[64 * 65];
    int tid = threadIdx.x, lane = tid & 63, w = tid >> 6;
    int m  = lane & 15;
    int kg = lane >> 4;
    int node0 = blockIdx.x * 64 + w * 16;

    int row = node0 + m; if (row >= NN) row = NN - 1;
    const ushort* hr = h_in + (size_t)row * H + kg * 8;
    bf16x8 a0 = *(const bf16x8*)(hr);
    bf16x8 a1 = *(const bf16x8*)(hr + 32);

    f32x4 acc0[4], acc1[4];
#pragma unroll
    for (int jt = 0; jt < 4; ++jt) {
        const ushort* wr0 = Wb + ((size_t)(jt * 16 + m)) * 64 + kg * 8;
        const ushort* wr1 = wr0 + (size_t)H * H;
        bf16x8 b00 = *(const bf16x8*)(wr0);
        bf16x8 b01 = *(const bf16x8*)(wr0 + 32);
        bf16x8 b10 = *(const bf16x8*)(wr1);
        bf16x8 b11 = *(const bf16x8*)(wr1 + 32);
        float bias = brel[jt * 16 + m];
        acc0[jt] = f32x4{0.f, 0.f, 0.f, 0.f};
        acc1[jt] = f32x4{bias, bias, bias, bias};
        acc0[jt] = __builtin_amdgcn_mfma_f32_16x16x32_bf16(a0, b00, acc0[jt], 0, 0, 0);
        acc0[jt] = __builtin_amdgcn_mfma_f32_16x16x32_bf16(a1, b01, acc0[jt], 0, 0, 0);
        acc1[jt] = __builtin_amdgcn_mfma_f32_16x16x32_bf16(a0, b10, acc1[jt], 0, 0, 0);
        acc1[jt] = __builtin_amdgcn_mfma_f32_16x16x32_bf16(a1, b11, acc1[jt], 0, 0, 0);
    }

    int nl = w * 16 + kg * 4;
    int nodeS0 = blockIdx.x * 64;

#pragma unroll
    for (int jt = 0; jt < 4; ++jt)
#pragma unroll
        for (int r = 0; r < 4; ++r)
            so[(nl + r) * 65 + jt * 16 + m] = acc0[jt][r];
    __syncthreads();
    for (int t = tid; t < 512; t += 256) {
        int rr = t >> 3, oct = t & 7;
        if (nodeS0 + rr < NN) {
            const float* s = &so[rr * 65 + oct * 8];
            uint4 v;
            v.x = (uint)f2bf(s[0]) | ((uint)f2bf(s[1]) << 16);
            v.y = (uint)f2bf(s[2]) | ((uint)f2bf(s[3]) << 16);
            v.z = (uint)f2bf(s[4]) | ((uint)f2bf(s[5]) << 16);
            v.w = (uint)f2bf(s[6]) | ((uint)f2bf(s[7]) << 16);
            *((uint4*)(z0 + (size_t)nodeS0 * H) + t) = v;
        }
    }
    __syncthreads();

#pragma unroll
    for (int jt = 0; jt < 4; ++jt)
#pragma unroll
        for (int r = 0; r < 4; ++r)
            so[(nl + r) * 65 + jt * 16 + m] = acc1[jt][r];
    __syncthreads();
    for (int t = tid; t < 512; t += 256) {
        int rr = t >> 3, oct = t & 7;
        if (nodeS0 + rr < NN) {
            const float* s = &so[rr * 65 + oct * 8];
            uint4 v;
            v.x = (uint)f2bf(s[0]) | ((uint)f2bf(s[1]) << 16);
            v.y = (uint)f2bf(s[2]) | ((uint)f2bf(s[3]) << 16);
            v.z = (uint)f2bf(s[4]) | ((uint)f2bf(s[5]) << 16);
            v.w = (uint)f2bf(s[6]) | ((uint)f2bf(s[7]) << 16);
            *((uint4*)(z1 + (size_t)nodeS0 * H) + t) = v;
        }
    }
}

// pure gather: h' = relu( sum_{j->n} z0[j] + z1[n] ).
// No LDS, no barriers; thread = (node n, oct); 8-deep predicated unroll
// puts a full degree-16 row's loads in flight in two rounds.
__global__ __launch_bounds__(256) void gather_relu_kernel(
    const ushort* __restrict__ z0, const ushort* __restrict__ z1,
    const int2* __restrict__ node_range, const int* __restrict__ edge_arr,
    ushort* __restrict__ h_out)
{
    int tid = blockIdx.x * 256 + threadIdx.x;
    int n = tid >> 3, oct = tid & 7;
    if (n >= NN) return;
    int2 rng = node_range[n];
    int p0 = rng.x, p1 = rng.x + rng.y;
    const char* zb = (const char*)z0 + oct * 16;
    float a[8] = {0.f,0.f,0.f,0.f,0.f,0.f,0.f,0.f};
    for (int p = p0; p < p1; p += 8) {
        bool g[8]; int o[8]; uint4 v[8];
#pragma unroll
        for (int q = 0; q < 8; ++q) {
            g[q] = (p + q) < p1;
            o[q] = g[q] ? edge_arr[p + q] : 0;
        }
#pragma unroll
        for (int q = 0; q < 8; ++q) {
            v[q] = make_uint4(0u, 0u, 0u, 0u);
            if (g[q]) v[q] = *(const uint4*)(zb + o[q]);
        }
#pragma unroll
        for (int q = 0; q < 8; ++q) {
            a[0] += bf_lo(v[q].x); a[1] += bf_hi(v[q].x);
            a[2] += bf_lo(v[q].y); a[3] += bf_hi(v[q].y);
            a[4] += bf_lo(v[q].z); a[5] += bf_hi(v[q].z);
            a[6] += bf_lo(v[q].w); a[7] += bf_hi(v[q].w);
        }
    }
    uint4 sv = *(const uint4*)((const char*)z1 + (size_t)n * 128 + oct * 16);
    a[0] += bf_lo(sv.x); a[1] += bf_hi(sv.x);
    a[2] += bf_lo(sv.y); a[3] += bf_hi(sv.y);
    a[4] += bf_lo(sv.z); a[5] += bf_hi(sv.z);
    a[6] += bf_lo(sv.w); a[7] += bf_hi(sv.w);
    uint4 o;
    o.x = (uint)f2bf(fmaxf(a[0], 0.f)) | ((uint)f2bf(fmaxf(a[1], 0.f)) << 16);
    o.y = (uint)f2bf(fmaxf(a[2], 0.f)) | ((uint)f2bf(fmaxf(a[3], 0.f)) << 16);
    o.z = (uint)f2bf(fmaxf(a[4], 0.f)) | ((uint)f2bf(fmaxf(a[5], 0.f)) << 16);
    o.w = (uint)f2bf(fmaxf(a[6], 0.f)) | ((uint)f2bf(fmaxf(a[7], 0.f)) << 16);
    *((uint4*)h_out + tid) = o;
}

// fused max-pool + MLP head: one block per graph
__global__ __launch_bounds__(256) void pool_mlp_kernel(
    const ushort* __restrict__ h, const int* __restrict__ batch,
    const float* __restrict__ fc1W, const float* __restrict__ fc1b,
    const float* __restrict__ fc2W, const float* __restrict__ fc2b,
    const float* __restrict__ fc3W, const float* __restrict__ fc3b,
    float* __restrict__ out)
{
    __shared__ float red[4][64];
    __shared__ float s0[64];
    __shared__ float s1[64];
    __shared__ float s2[64];
    int b = blockIdx.x;
    int tid = threadIdx.x;
    int f = tid & 63, w = tid >> 6;
    int lo = 0, hi = NN;
    while (lo < hi) { int mid = (lo + hi) >> 1; if (batch[mid] < b) lo = mid + 1; else hi = mid; }
    int lo2 = lo, hi2 = NN;
    while (lo2 < hi2) { int mid = (lo2 + hi2) >> 1; if (batch[mid] < b + 1) lo2 = mid + 1; else hi2 = mid; }
    float m = -3.402823466e38f;
    for (int n = lo + w; n < lo2; n += 4) {
        ushort u = h[(size_t)n * H + f];
        m = fmaxf(m, __uint_as_float((uint)u << 16));
    }
    red[w][f] = m;
    __syncthreads();
    int j = tid;
    if (tid < 64)
        s0[j] = fmaxf(fmaxf(red[0][j], red[1][j]), fmaxf(red[2][j], red[3][j]));
    __syncthreads();
    float acc = 0.f;
    if (tid < 64) {
        acc = fc1b[j];
        for (int k = 0; k < 64; ++k) acc = fmaf(s0[k], fc1W[j * 64 + k], acc);
    }
    __syncthreads();
    if (tid < 64) s1[j] = fmaxf(acc, 0.f);
    __syncthreads();
    if (tid < 64) {
        acc = fc2b[j];
        for (int k = 0; k < 64; ++k) acc = fmaf(s1[k], fc2W[j * 64 + k], acc);
    }
    __syncthreads();
    if (tid < 64) s2[j] = fmaxf(acc, 0.f);
    __syncthreads();
    if (tid < NC) {
        acc = fc3b[j];
        for (int k = 0; k < 64; ++k) acc = fmaf(s2[k], fc3W[j * 64 + k], acc);
        out[b * NC + j] = acc;
    }
}

// ---------------- launcher ----------------

extern "C" void kernel_launch(void* const* d_in, const int* in_sizes, int n_in,
                              void* d_out, int out_size, void* d_ws, size_t ws_size,
                              hipStream_t stream)
{
    const float* x         = (const float*)d_in[0];
    const int*   dst_ports = (const int*)d_in[1];
    const int*   tcp_flags = (const int*)d_in[2];
    const int*   edge_src_in = (const int*)d_in[3];          // row 0 of (2,E)
    const int*   edge_dst_in = edge_src_in + NE;             // row 1
    const int*   batch     = (const int*)d_in[4];
    const float* emb_port  = (const float*)d_in[5];
    const float* emb_flags = (const float*)d_in[6];
    const float* Wrel      = (const float*)d_in[7];
    const float* brel      = (const float*)d_in[8];
    const float* Wroot     = (const float*)d_in[9];
    const float* fc1W      = (const float*)d_in[10];
    const float* fc1b      = (const float*)d_in[11];
    const float* fc2W      = (const float*)d_in[12];
    const float* fc2b      = (const float*)d_in[13];
    const float* fc3W      = (const float*)d_in[14];
    const float* fc3b      = (const float*)d_in[15];
    float* out = (float*)d_out;

    // workspace carve-up (256B aligned)
    char* ws = (char*)d_ws;
    size_t off = 0;
    auto alloc = [&](size_t bytes) {
        void* p = ws + off;
        off += (bytes + 255) & ~(size_t)255;
        return p;
    };
    ushort* hA        = (ushort*)alloc((size_t)NN * H * 2);
    ushort* hB        = (ushort*)alloc((size_t)NN * H * 2);
    ushort* z0        = (ushort*)alloc((size_t)NN * H * 2);
    ushort* z1        = (ushort*)alloc((size_t)NN * H * 2);
    int2*   tmp       = (int2*)alloc((size_t)NBK * BKCAP * 8);
    int*    edge_arr  = (int*)alloc((size_t)NBK * BKCAP * 4);
    int2*   node_range= (int2*)alloc((size_t)NN * 8);
    int*    bcnt      = (int*)alloc((size_t)NBK * BSTRIDE * 4);
    ushort* Wb        = (ushort*)alloc((size_t)L * 2 * H * H * 2);

    // weight conversion + zero padded bucket counters
    prep_weights_kernel<<<96, 256, 0, stream>>>(Wrel, Wroot, Wb, bcnt);

    // CSR via padded-counter bucket sort (contention-calibrated)
    bucketA_kernel<<<(NE + 255) / 256, 256, 0, stream>>>(edge_src_in, edge_dst_in, bcnt, tmp);
    bucketB_kernel<<<NBK, 64, 0, stream>>>(tmp, bcnt, edge_arr, node_range);

    // layer 0: fused embed + MFMA gemm, then gather
    const int ggrid = (NN + 63) / 64;
    const int agrid = (NN * 8 + 255) / 256;
    gemm0_fused_kernel<<<ggrid, 256, 0, stream>>>(
        x, dst_ports, tcp_flags, emb_port, emb_flags, Wb, brel, z0, z1);
    gather_relu_kernel<<<agrid, 256, 0, stream>>>(z0, z1, node_range, edge_arr, hA);

    // layers 1,2
    gemm_kernel<<<ggrid, 256, 0, stream>>>(
        hA, Wb + (size_t)1 * 2 * H * H, brel + 1 * H, z0, z1);
    gather_relu_kernel<<<agrid, 256, 0, stream>>>(z0, z1, node_range, edge_arr, hB);
    gemm_kernel<<<ggrid, 256, 0, stream>>>(
        hB, Wb + (size_t)2 * 2 * H * H, brel + 2 * H, z0, z1);
    gather_relu_kernel<<<agrid, 256, 0, stream>>>(z0, z1, node_range, edge_arr, hA);

    // fused global max pool + MLP head
    pool_mlp_kernel<<<NB, 256, 0, stream>>>(
        hA, batch, fc1W, fc1b, fc2W, fc2b, fc3W, fc3b, out);
}

// Round 12
// 272.282 us; speedup vs baseline: 1.8947x; 1.0736x over previous
//
#include <hip/hip_runtime.h>

#define NN 50000
#define NE 800000
#define NB 128
#define FIN 30
#define H 64
#define NC 10
#define L 3

#define EBS 2048              // edges per chunk
#define NEB 391               // ceil(NE / EBS)
#define NBX 391               // dst buckets (dst >> 7), 128 nodes each
#define NS (NBX * NEB)        // counts array size = 152881
#define SECAP 2816            // LDS edge stage capacity per bucket (lambda=2048, +17 sigma)

typedef unsigned int uint;
typedef unsigned short ushort;
typedef __attribute__((ext_vector_type(8))) short bf16x8;
typedef __attribute__((ext_vector_type(4))) float f32x4;

// f32 -> bf16 round-to-nearest-even (finite inputs)
__device__ __forceinline__ ushort f2bf(float x) {
    uint u = __float_as_uint(x);
    u += 0x7fffu + ((u >> 16) & 1u);
    return (ushort)(u >> 16);
}
__device__ __forceinline__ float bf_lo(uint v) { return __uint_as_float(v << 16); }
__device__ __forceinline__ float bf_hi(uint v) { return __uint_as_float(v & 0xffff0000u); }

// ---------------- kernels ----------------

// weights f32 -> bf16 (Wb[l][mat][j][k])
__global__ __launch_bounds__(256) void prep_weights_kernel(
    const float* __restrict__ Wrel, const float* __restrict__ Wroot,
    ushort* __restrict__ Wb)
{
    int t = blockIdx.x * 256 + threadIdx.x;
    if (t >= L * 2 * H * H) return;
    int l = t / (2 * H * H), rem = t % (2 * H * H);
    int mat = rem / (H * H), jk = rem % (H * H);
    const float* W = mat ? Wroot : Wrel;
    Wb[t] = f2bf(W[l * H * H + jk]);
}

// radix pass 1: per-chunk per-bucket counts (LDS hist, no global atomics)
__global__ __launch_bounds__(256) void count_kernel(
    const int* __restrict__ dst, int* __restrict__ counts)
{
    __shared__ int cnt[NBX];
    int eb = blockIdx.x, tid = threadIdx.x;
    for (int t = tid; t < NBX; t += 256) cnt[t] = 0;
    __syncthreads();
#pragma unroll
    for (int q = 0; q < 8; ++q) {
        int e = eb * EBS + q * 256 + tid;
        if (e < NE) atomicAdd(&cnt[dst[e] >> 7], 1);
    }
    __syncthreads();
    for (int t = tid; t < NBX; t += 256) counts[t * NEB + eb] = cnt[t];
}

// exclusive scan over counts[NS]: per-block exclusive + block totals
__global__ __launch_bounds__(1024) void scanA1_kernel(
    const int* __restrict__ counts, int* __restrict__ offs, int* __restrict__ bsum)
{
    __shared__ int wsum[16];
    int i = blockIdx.x * 1024 + threadIdx.x;
    int lane = threadIdx.x & 63;
    int wv = threadIdx.x >> 6;
    int v = (i < NS) ? counts[i] : 0;
    int s = v;
    for (int off = 1; off < 64; off <<= 1) {
        int t = __shfl_up(s, off);
        if (lane >= off) s += t;
    }
    if (lane == 63) wsum[wv] = s;
    __syncthreads();
    if (wv == 0) {
        int ws = (lane < 16) ? wsum[lane] : 0;
        for (int off = 1; off < 16; off <<= 1) {
            int t = __shfl_up(ws, off);
            if (lane >= off) ws += t;
        }
        if (lane < 16) wsum[lane] = ws;
    }
    __syncthreads();
    int base = (wv > 0) ? wsum[wv - 1] : 0;
    s += base;                       // inclusive within block
    if (i < NS) offs[i] = s - v;     // exclusive within block
    if (threadIdx.x == 1023) bsum[blockIdx.x] = s;  // block total
}

// scan the 150 block totals -> exclusive carries (one 256-thread block)
__global__ __launch_bounds__(256) void scanA2_kernel(int* __restrict__ bsum, int nblk)
{
    __shared__ int arr[256];
    int t = threadIdx.x;
    int v = (t < nblk) ? bsum[t] : 0;
    arr[t] = v;
    __syncthreads();
    for (int off = 1; off < 256; off <<= 1) {
        int u = (t >= off) ? arr[t - off] : 0;
        __syncthreads();
        arr[t] += u;
        __syncthreads();
    }
    if (t < nblk) bsum[t] = arr[t] - v;   // exclusive
}

__global__ __launch_bounds__(1024) void scanA3_kernel(
    int* __restrict__ offs, const int* __restrict__ bsum)
{
    int b = blockIdx.x + 1;
    int i = b * 1024 + threadIdx.x;
    if (i < NS) offs[i] += bsum[b];
}

// radix pass 2: rank-based scatter (no global atomics; exact final positions).
// tmp[pos] = (src<<7) | (dst & 127)
__global__ __launch_bounds__(256) void scatter_ranked_kernel(
    const int* __restrict__ src, const int* __restrict__ dst,
    const int* __restrict__ offs, int* __restrict__ tmp)
{
    __shared__ int cur[NBX];
    int eb = blockIdx.x, tid = threadIdx.x;
    for (int t = tid; t < NBX; t += 256) cur[t] = offs[t * NEB + eb];
    __syncthreads();
#pragma unroll
    for (int q = 0; q < 8; ++q) {
        int e = eb * EBS + q * 256 + tid;
        if (e < NE) {
            int d = dst[e];
            int b = d >> 7;
            int pos = atomicAdd(&cur[b], 1);
            tmp[pos] = (src[e] << 7) | (d & 127);
        }
    }
}

// radix pass 3: per-bucket counting sort by node -> edge_arr (src byte offsets)
// + node_range. All writes confined to this bucket's contiguous region.
__global__ __launch_bounds__(256) void bucket_sort_kernel(
    const int* __restrict__ tmp, const int* __restrict__ offs,
    int* __restrict__ edge_arr, int2* __restrict__ node_range)
{
    __shared__ int se[SECAP];
    __shared__ int cnt[128];
    __shared__ int off[128];
    __shared__ int cur[128];
    int b = blockIdx.x, tid = threadIdx.x;
    int start = offs[b * NEB];
    int end   = (b + 1 < NBX) ? offs[(b + 1) * NEB] : NE;
    int ec = end - start; if (ec > SECAP) ec = SECAP;

    if (tid < 128) cnt[tid] = 0;
    __syncthreads();
    for (int t = tid; t < ec; t += 256) {
        int v = tmp[start + t];
        se[t] = v;
        atomicAdd(&cnt[v & 127], 1);
    }
    __syncthreads();
    if (tid < 64) {   // wave 0: exclusive scan of 128 counts (2 per lane)
        int v0 = cnt[2 * tid], v1 = cnt[2 * tid + 1];
        int s = v0 + v1;
        for (int o = 1; o < 64; o <<= 1) {
            int t = __shfl_up(s, o);
            if (tid >= o) s += t;
        }
        off[2 * tid]     = s - v1 - v0;
        off[2 * tid + 1] = s - v1;
        cur[2 * tid]     = s - v1 - v0;
        cur[2 * tid + 1] = s - v1;
    }
    __syncthreads();
    for (int t = tid; t < ec; t += 256) {
        int v = se[t];
        int p = atomicAdd(&cur[v & 127], 1);
        edge_arr[start + p] = v & ~127;      // pure src byte offset
    }
    if (tid < 128) {
        int n = b * 128 + tid;
        if (n < NN) node_range[n] = make_int2(start + off[tid], cnt[tid]);
    }
}

// fused embed + MFMA GEMM for layer 0
__global__ __launch_bounds__(256) void gemm0_fused_kernel(
    const float* __restrict__ x, const int* __restrict__ ports,
    const int* __restrict__ flags, const float* __restrict__ emb_port,
    const float* __restrict__ emb_flags,
    const ushort* __restrict__ Wb, const float* __restrict__ brel,
    ushort* __restrict__ z0, ushort* __restrict__ z1)
{
    __shared__ float sf[64 * 65];
    __shared__ float so[64 * 65];
    int tid = threadIdx.x, lane = tid & 63, w = tid >> 6;
    int node0 = blockIdx.x * 64;

    for (int t = tid; t < 4096; t += 256) {
        int r = t >> 6, f = t & 63;
        int n = node0 + r;
        float v = 0.f;
        if (n < NN) {
            if (f < FIN)       v = x[(size_t)n * FIN + f];
            else if (f < 62)   v = emb_port[(size_t)ports[n] * 32 + (f - FIN)];
            else               v = emb_flags[(size_t)flags[n] * 2 + (f - 62)];
        }
        sf[r * 65 + f] = v;
    }
    __syncthreads();

    int m  = lane & 15;
    int kg = lane >> 4;
    int rloc = w * 16 + m;
    const float* fr = &sf[rloc * 65 + kg * 8];
    bf16x8 a0, a1;
#pragma unroll
    for (int i = 0; i < 8; ++i) {
        a0[i] = (short)f2bf(fr[i]);
        a1[i] = (short)f2bf(fr[32 + i]);
    }

    f32x4 acc0[4], acc1[4];
#pragma unroll
    for (int jt = 0; jt < 4; ++jt) {
        const ushort* wr0 = Wb + ((size_t)(jt * 16 + m)) * 64 + kg * 8;
        const ushort* wr1 = wr0 + (size_t)H * H;
        bf16x8 b00 = *(const bf16x8*)(wr0);
        bf16x8 b01 = *(const bf16x8*)(wr0 + 32);
        bf16x8 b10 = *(const bf16x8*)(wr1);
        bf16x8 b11 = *(const bf16x8*)(wr1 + 32);
        float bias = brel[jt * 16 + m];
        acc0[jt] = f32x4{0.f, 0.f, 0.f, 0.f};
        acc1[jt] = f32x4{bias, bias, bias, bias};
        acc0[jt] = __builtin_amdgcn_mfma_f32_16x16x32_bf16(a0, b00, acc0[jt], 0, 0, 0);
        acc0[jt] = __builtin_amdgcn_mfma_f32_16x16x32_bf16(a1, b01, acc0[jt], 0, 0, 0);
        acc1[jt] = __builtin_amdgcn_mfma_f32_16x16x32_bf16(a0, b10, acc1[jt], 0, 0, 0);
        acc1[jt] = __builtin_amdgcn_mfma_f32_16x16x32_bf16(a1, b11, acc1[jt], 0, 0, 0);
    }

    int nl = w * 16 + kg * 4;

#pragma unroll
    for (int jt = 0; jt < 4; ++jt)
#pragma unroll
        for (int r = 0; r < 4; ++r)
            so[(nl + r) * 65 + jt * 16 + m] = acc0[jt][r];
    __syncthreads();
    for (int t = tid; t < 512; t += 256) {
        int rr = t >> 3, oct = t & 7;
        if (node0 + rr < NN) {
            const float* s = &so[rr * 65 + oct * 8];
            uint4 v;
            v.x = (uint)f2bf(s[0]) | ((uint)f2bf(s[1]) << 16);
            v.y = (uint)f2bf(s[2]) | ((uint)f2bf(s[3]) << 16);
            v.z = (uint)f2bf(s[4]) | ((uint)f2bf(s[5]) << 16);
            v.w = (uint)f2bf(s[6]) | ((uint)f2bf(s[7]) << 16);
            *((uint4*)(z0 + (size_t)node0 * H) + t) = v;
        }
    }
    __syncthreads();

#pragma unroll
    for (int jt = 0; jt < 4; ++jt)
#pragma unroll
        for (int r = 0; r < 4; ++r)
            so[(nl + r) * 65 + jt * 16 + m] = acc1[jt][r];
    __syncthreads();
    for (int t = tid; t < 512; t += 256) {
        int rr = t >> 3, oct = t & 7;
        if (node0 + rr < NN) {
            const float* s = &so[rr * 65 + oct * 8];
            uint4 v;
            v.x = (uint)f2bf(s[0]) | ((uint)f2bf(s[1]) << 16);
            v.y = (uint)f2bf(s[2]) | ((uint)f2bf(s[3]) << 16);
            v.z = (uint)f2bf(s[4]) | ((uint)f2bf(s[5]) << 16);
            v.w = (uint)f2bf(s[6]) | ((uint)f2bf(s[7]) << 16);
            *((uint4*)(z1 + (size_t)node0 * H) + t) = v;
        }
    }
}

// MFMA GEMMs (layers 1,2)
__global__ __launch_bounds__(256) void gemm_kernel(
    const ushort* __restrict__ h_in, const ushort* __restrict__ Wb,
    const float* __restrict__ brel,
    ushort* __restrict__ z0, ushort* __restrict__ z1)
{
    __shared__ float so[64 * 65];
    int tid = threadIdx.x, lane = tid & 63, w = tid >> 6;
    int m  = lane & 15;
    int kg = lane >> 4;
    int node0 = blockIdx.x * 64 + w * 16;

    int row = node0 + m; if (row >= NN) row = NN - 1;
    const ushort* hr = h_in + (size_t)row * H + kg * 8;
    bf16x8 a0 = *(const bf16x8*)(hr);
    bf16x8 a1 = *(const bf16x8*)(hr + 32);

    f32x4 acc0[4], acc1[4];
#pragma unroll
    for (int jt = 0; jt < 4; ++jt) {
        const ushort* wr0 = Wb + ((size_t)(jt * 16 + m)) * 64 + kg * 8;
        const ushort* wr1 = wr0 + (size_t)H * H;
        bf16x8 b00 = *(const bf16x8*)(wr0);
        bf16x8 b01 = *(const bf16x8*)(wr0 + 32);
        bf16x8 b10 = *(const bf16x8*)(wr1);
        bf16x8 b11 = *(const bf16x8*)(wr1 + 32);
        float bias = brel[jt * 16 + m];
        acc0[jt] = f32x4{0.f, 0.f, 0.f, 0.f};
        acc1[jt] = f32x4{bias, bias, bias, bias};
        acc0[jt] = __builtin_amdgcn_mfma_f32_16x16x32_bf16(a0, b00, acc0[jt], 0, 0, 0);
        acc0[jt] = __builtin_amdgcn_mfma_f32_16x16x32_bf16(a1, b01, acc0[jt], 0, 0, 0);
        acc1[jt] = __builtin_amdgcn_mfma_f32_16x16x32_bf16(a0, b10, acc1[jt], 0, 0, 0);
        acc1[jt] = __builtin_amdgcn_mfma_f32_16x16x32_bf16(a1, b11, acc1[jt], 0, 0, 0);
    }

    int nl = w * 16 + kg * 4;
    int nodeS0 = blockIdx.x * 64;

#pragma unroll
    for (int jt = 0; jt < 4; ++jt)
#pragma unroll
        for (int r = 0; r < 4; ++r)
            so[(nl + r) * 65 + jt * 16 + m] = acc0[jt][r];
    __syncthreads();
    for (int t = tid; t < 512; t += 256) {
        int rr = t >> 3, oct = t & 7;
        if (nodeS0 + rr < NN) {
            const float* s = &so[rr * 65 + oct * 8];
            uint4 v;
            v.x = (uint)f2bf(s[0]) | ((uint)f2bf(s[1]) << 16);
            v.y = (uint)f2bf(s[2]) | ((uint)f2bf(s[3]) << 16);
            v.z = (uint)f2bf(s[4]) | ((uint)f2bf(s[5]) << 16);
            v.w = (uint)f2bf(s[6]) | ((uint)f2bf(s[7]) << 16);
            *((uint4*)(z0 + (size_t)nodeS0 * H) + t) = v;
        }
    }
    __syncthreads();

#pragma unroll
    for (int jt = 0; jt < 4; ++jt)
#pragma unroll
        for (int r = 0; r < 4; ++r)
            so[(nl + r) * 65 + jt * 16 + m] = acc1[jt][r];
    __syncthreads();
    for (int t = tid; t < 512; t += 256) {
        int rr = t >> 3, oct = t & 7;
        if (nodeS0 + rr < NN) {
            const float* s = &so[rr * 65 + oct * 8];
            uint4 v;
            v.x = (uint)f2bf(s[0]) | ((uint)f2bf(s[1]) << 16);
            v.y = (uint)f2bf(s[2]) | ((uint)f2bf(s[3]) << 16);
            v.z = (uint)f2bf(s[4]) | ((uint)f2bf(s[5]) << 16);
            v.w = (uint)f2bf(s[6]) | ((uint)f2bf(s[7]) << 16);
            *((uint4*)(z1 + (size_t)nodeS0 * H) + t) = v;
        }
    }
}

// pure gather: h' = relu( sum_{j->n} z0[j] + z1[n] ); 8-deep predicated unroll
__global__ __launch_bounds__(256) void gather_relu_kernel(
    const ushort* __restrict__ z0, const ushort* __restrict__ z1,
    const int2* __restrict__ node_range, const int* __restrict__ edge_arr,
    ushort* __restrict__ h_out)
{
    int tid = blockIdx.x * 256 + threadIdx.x;
    int n = tid >> 3, oct = tid & 7;
    if (n >= NN) return;
    int2 rng = node_range[n];
    int p0 = rng.x, p1 = rng.x + rng.y;
    const char* zb = (const char*)z0 + oct * 16;
    float a[8] = {0.f,0.f,0.f,0.f,0.f,0.f,0.f,0.f};
    for (int p = p0; p < p1; p += 8) {
        bool g[8]; int o[8]; uint4 v[8];
#pragma unroll
        for (int q = 0; q < 8; ++q) {
            g[q] = (p + q) < p1;
            o[q] = g[q] ? edge_arr[p + q] : 0;
        }
#pragma unroll
        for (int q = 0; q < 8; ++q) {
            v[q] = make_uint4(0u, 0u, 0u, 0u);
            if (g[q]) v[q] = *(const uint4*)(zb + o[q]);
        }
#pragma unroll
        for (int q = 0; q < 8; ++q) {
            a[0] += bf_lo(v[q].x); a[1] += bf_hi(v[q].x);
            a[2] += bf_lo(v[q].y); a[3] += bf_hi(v[q].y);
            a[4] += bf_lo(v[q].z); a[5] += bf_hi(v[q].z);
            a[6] += bf_lo(v[q].w); a[7] += bf_hi(v[q].w);
        }
    }
    uint4 sv = *(const uint4*)((const char*)z1 + (size_t)n * 128 + oct * 16);
    a[0] += bf_lo(sv.x); a[1] += bf_hi(sv.x);
    a[2] += bf_lo(sv.y); a[3] += bf_hi(sv.y);
    a[4] += bf_lo(sv.z); a[5] += bf_hi(sv.z);
    a[6] += bf_lo(sv.w); a[7] += bf_hi(sv.w);
    uint4 o;
    o.x = (uint)f2bf(fmaxf(a[0], 0.f)) | ((uint)f2bf(fmaxf(a[1], 0.f)) << 16);
    o.y = (uint)f2bf(fmaxf(a[2], 0.f)) | ((uint)f2bf(fmaxf(a[3], 0.f)) << 16);
    o.z = (uint)f2bf(fmaxf(a[4], 0.f)) | ((uint)f2bf(fmaxf(a[5], 0.f)) << 16);
    o.w = (uint)f2bf(fmaxf(a[6], 0.f)) | ((uint)f2bf(fmaxf(a[7], 0.f)) << 16);
    *((uint4*)h_out + tid) = o;
}

// fused max-pool + MLP head: one block per graph
__global__ __launch_bounds__(256) void pool_mlp_kernel(
    const ushort* __restrict__ h, const int* __restrict__ batch,
    const float* __restrict__ fc1W, const float* __restrict__ fc1b,
    const float* __restrict__ fc2W, const float* __restrict__ fc2b,
    const float* __restrict__ fc3W, const float* __restrict__ fc3b,
    float* __restrict__ out)
{
    __shared__ float red[4][64];
    __shared__ float s0[64];
    __shared__ float s1[64];
    __shared__ float s2[64];
    int b = blockIdx.x;
    int tid = threadIdx.x;
    int f = tid & 63, w = tid >> 6;
    int lo = 0, hi = NN;
    while (lo < hi) { int mid = (lo + hi) >> 1; if (batch[mid] < b) lo = mid + 1; else hi = mid; }
    int lo2 = lo, hi2 = NN;
    while (lo2 < hi2) { int mid = (lo2 + hi2) >> 1; if (batch[mid] < b + 1) lo2 = mid + 1; else hi2 = mid; }
    float m = -3.402823466e38f;
    for (int n = lo + w; n < lo2; n += 4) {
        ushort u = h[(size_t)n * H + f];
        m = fmaxf(m, __uint_as_float((uint)u << 16));
    }
    red[w][f] = m;
    __syncthreads();
    int j = tid;
    if (tid < 64)
        s0[j] = fmaxf(fmaxf(red[0][j], red[1][j]), fmaxf(red[2][j], red[3][j]));
    __syncthreads();
    float acc = 0.f;
    if (tid < 64) {
        acc = fc1b[j];
        for (int k = 0; k < 64; ++k) acc = fmaf(s0[k], fc1W[j * 64 + k], acc);
    }
    __syncthreads();
    if (tid < 64) s1[j] = fmaxf(acc, 0.f);
    __syncthreads();
    if (tid < 64) {
        acc = fc2b[j];
        for (int k = 0; k < 64; ++k) acc = fmaf(s1[k], fc2W[j * 64 + k], acc);
    }
    __syncthreads();
    if (tid < 64) s2[j] = fmaxf(acc, 0.f);
    __syncthreads();
    if (tid < NC) {
        acc = fc3b[j];
        for (int k = 0; k < 64; ++k) acc = fmaf(s2[k], fc3W[j * 64 + k], acc);
        out[b * NC + j] = acc;
    }
}

// ---------------- launcher ----------------

extern "C" void kernel_launch(void* const* d_in, const int* in_sizes, int n_in,
                              void* d_out, int out_size, void* d_ws, size_t ws_size,
                              hipStream_t stream)
{
    const float* x         = (const float*)d_in[0];
    const int*   dst_ports = (const int*)d_in[1];
    const int*   tcp_flags = (const int*)d_in[2];
    const int*   edge_src_in = (const int*)d_in[3];          // row 0 of (2,E)
    const int*   edge_dst_in = edge_src_in + NE;             // row 1
    const int*   batch     = (const int*)d_in[4];
    const float* emb_port  = (const float*)d_in[5];
    const float* emb_flags = (const float*)d_in[6];
    const float* Wrel      = (const float*)d_in[7];
    const float* brel      = (const float*)d_in[8];
    const float* Wroot     = (const float*)d_in[9];
    const float* fc1W      = (const float*)d_in[10];
    const float* fc1b      = (const float*)d_in[11];
    const float* fc2W      = (const float*)d_in[12];
    const float* fc2b      = (const float*)d_in[13];
    const float* fc3W      = (const float*)d_in[14];
    const float* fc3b      = (const float*)d_in[15];
    float* out = (float*)d_out;

    // workspace carve-up (256B aligned)
    char* ws = (char*)d_ws;
    size_t off = 0;
    auto alloc = [&](size_t bytes) {
        void* p = ws + off;
        off += (bytes + 255) & ~(size_t)255;
        return p;
    };
    ushort* hA        = (ushort*)alloc((size_t)NN * H * 2);
    ushort* hB        = (ushort*)alloc((size_t)NN * H * 2);
    ushort* z0        = (ushort*)alloc((size_t)NN * H * 2);
    ushort* z1        = (ushort*)alloc((size_t)NN * H * 2);
    int*    counts    = (int*)alloc((size_t)NS * 4);      // doubles as offs (in place)
    int*    tmp       = (int*)alloc((size_t)NE * 4);
    int*    edge_arr  = (int*)alloc((size_t)NE * 4);
    int2*   node_range= (int2*)alloc((size_t)NN * 8);
    int*    bsum      = (int*)alloc((size_t)256 * 4);
    ushort* Wb        = (ushort*)alloc((size_t)L * 2 * H * H * 2);

    const int SBLK = (NS + 1023) / 1024;   // 150 scan blocks

    // weight conversion (tiny)
    prep_weights_kernel<<<96, 256, 0, stream>>>(Wrel, Wroot, Wb);

    // rank-based radix CSR (no global atomics, no random-write amplification)
    count_kernel<<<NEB, 256, 0, stream>>>(edge_dst_in, counts);
    scanA1_kernel<<<SBLK, 1024, 0, stream>>>(counts, counts, bsum);   // in-place excl scan
    scanA2_kernel<<<1, 256, 0, stream>>>(bsum, SBLK);
    scanA3_kernel<<<SBLK - 1, 1024, 0, stream>>>(counts, bsum);
    scatter_ranked_kernel<<<NEB, 256, 0, stream>>>(edge_src_in, edge_dst_in, counts, tmp);
    bucket_sort_kernel<<<NBX, 256, 0, stream>>>(tmp, counts, edge_arr, node_range);

    // layer 0: fused embed + MFMA gemm, then gather
    const int ggrid = (NN + 63) / 64;
    const int agrid = (NN * 8 + 255) / 256;
    gemm0_fused_kernel<<<ggrid, 256, 0, stream>>>(
        x, dst_ports, tcp_flags, emb_port, emb_flags, Wb, brel, z0, z1);
    gather_relu_kernel<<<agrid, 256, 0, stream>>>(z0, z1, node_range, edge_arr, hA);

    // layers 1,2
    gemm_kernel<<<ggrid, 256, 0, stream>>>(
        hA, Wb + (size_t)1 * 2 * H * H, brel + 1 * H, z0, z1);
    gather_relu_kernel<<<agrid, 256, 0, stream>>>(z0, z1, node_range, edge_arr, hB);
    gemm_kernel<<<ggrid, 256, 0, stream>>>(
        hB, Wb + (size_t)2 * 2 * H * H, brel + 2 * H, z0, z1);
    gather_relu_kernel<<<agrid, 256, 0, stream>>>(z0, z1, node_range, edge_arr, hA);

    // fused global max pool + MLP head
    pool_mlp_kernel<<<NB, 256, 0, stream>>>(
        hA, batch, fc1W, fc1b, fc2W, fc2b, fc3W, fc3b, out);
}

// Round 13
// 243.183 us; speedup vs baseline: 2.1214x; 1.1197x over previous
//
#include <hip/hip_runtime.h>

#define NN 50000
#define NE 800000
#define NB 128
#define FIN 30
#define H 64
#define NC 10
#define L 3

#define EBS 2048              // edges per chunk
#define NEB 391               // ceil(NE / EBS)
#define NBX 391               // dst buckets (dst >> 7), 128 nodes each
#define NS (NBX * NEB)        // counts array size = 152881
#define SECAP 2816            // LDS edge stage capacity per bucket (+17 sigma)
#define PCAP 3456             // padded per-bucket edge_arr stride (+11 sigma incl. padding)
#define ZOFF (NN << 7)        // byte offset of the zero row (row NN of z0)

typedef unsigned int uint;
typedef unsigned short ushort;
typedef __attribute__((ext_vector_type(8))) short bf16x8;
typedef __attribute__((ext_vector_type(4))) float f32x4;

// f32 -> bf16 round-to-nearest-even (finite inputs)
__device__ __forceinline__ ushort f2bf(float x) {
    uint u = __float_as_uint(x);
    u += 0x7fffu + ((u >> 16) & 1u);
    return (ushort)(u >> 16);
}
__device__ __forceinline__ float bf_lo(uint v) { return __uint_as_float(v << 16); }
__device__ __forceinline__ float bf_hi(uint v) { return __uint_as_float(v & 0xffff0000u); }

// ---------------- kernels ----------------

// fused: blocks [0,NEB) = radix count; [NEB, NEB+96) = weight bf16 convert;
// block NEB+96 = zero-row init for gather padding.
__global__ __launch_bounds__(256) void count_prep_kernel(
    const int* __restrict__ dst, int* __restrict__ counts,
    const float* __restrict__ Wrel, const float* __restrict__ Wroot,
    ushort* __restrict__ Wb, ushort* __restrict__ z0)
{
    __shared__ int cnt[NBX];
    int bid = blockIdx.x, tid = threadIdx.x;
    if (bid < NEB) {
        for (int t = tid; t < NBX; t += 256) cnt[t] = 0;
        __syncthreads();
#pragma unroll
        for (int q = 0; q < 8; ++q) {
            int e = bid * EBS + q * 256 + tid;
            if (e < NE) atomicAdd(&cnt[dst[e] >> 7], 1);
        }
        __syncthreads();
        for (int t = tid; t < NBX; t += 256) counts[t * NEB + bid] = cnt[t];
    } else if (bid < NEB + 96) {
        int t = (bid - NEB) * 256 + tid;
        if (t < L * 2 * H * H) {
            int l = t / (2 * H * H), rem = t % (2 * H * H);
            int mat = rem / (H * H), jk = rem % (H * H);
            const float* W = mat ? Wroot : Wrel;
            Wb[t] = f2bf(W[l * H * H + jk]);
        }
    } else {
        if (tid < 8) ((uint4*)(z0 + (size_t)NN * H))[tid] = make_uint4(0u, 0u, 0u, 0u);
    }
}

// exclusive scan over counts[NS]: per-block exclusive + block totals
__global__ __launch_bounds__(1024) void scanA1_kernel(
    const int* __restrict__ counts, int* __restrict__ offs, int* __restrict__ bsum)
{
    __shared__ int wsum[16];
    int i = blockIdx.x * 1024 + threadIdx.x;
    int lane = threadIdx.x & 63;
    int wv = threadIdx.x >> 6;
    int v = (i < NS) ? counts[i] : 0;
    int s = v;
    for (int off = 1; off < 64; off <<= 1) {
        int t = __shfl_up(s, off);
        if (lane >= off) s += t;
    }
    if (lane == 63) wsum[wv] = s;
    __syncthreads();
    if (wv == 0) {
        int ws = (lane < 16) ? wsum[lane] : 0;
        for (int off = 1; off < 16; off <<= 1) {
            int t = __shfl_up(ws, off);
            if (lane >= off) ws += t;
        }
        if (lane < 16) wsum[lane] = ws;
    }
    __syncthreads();
    int base = (wv > 0) ? wsum[wv - 1] : 0;
    s += base;
    if (i < NS) offs[i] = s - v;
    if (threadIdx.x == 1023) bsum[blockIdx.x] = s;
}

__global__ __launch_bounds__(256) void scanA2_kernel(int* __restrict__ bsum, int nblk)
{
    __shared__ int arr[256];
    int t = threadIdx.x;
    int v = (t < nblk) ? bsum[t] : 0;
    arr[t] = v;
    __syncthreads();
    for (int off = 1; off < 256; off <<= 1) {
        int u = (t >= off) ? arr[t - off] : 0;
        __syncthreads();
        arr[t] += u;
        __syncthreads();
    }
    if (t < nblk) bsum[t] = arr[t] - v;
}

__global__ __launch_bounds__(1024) void scanA3_kernel(
    int* __restrict__ offs, const int* __restrict__ bsum)
{
    int b = blockIdx.x + 1;
    int i = b * 1024 + threadIdx.x;
    if (i < NS) offs[i] += bsum[b];
}

// fused: blocks [0,NEB) = ranked scatter; [NEB, NEB+782) = embed+MFMA gemm0.
// Independent work, runs concurrently in one dispatch.
__global__ __launch_bounds__(256) void scatter_gemm0_kernel(
    const int* __restrict__ srcv, const int* __restrict__ dstv,
    const int* __restrict__ offs, int* __restrict__ tmp,
    const float* __restrict__ x, const int* __restrict__ ports,
    const int* __restrict__ flags, const float* __restrict__ emb_port,
    const float* __restrict__ emb_flags,
    const ushort* __restrict__ Wb, const float* __restrict__ brel,
    ushort* __restrict__ z0, ushort* __restrict__ z1)
{
    __shared__ float sf[64 * 65];
    __shared__ float so[64 * 65];
    __shared__ int cur[NBX];
    int bid = blockIdx.x, tid = threadIdx.x;

    if (bid < NEB) {
        // ---- ranked scatter role ----
        for (int t = tid; t < NBX; t += 256) cur[t] = offs[t * NEB + bid];
        __syncthreads();
#pragma unroll
        for (int q = 0; q < 8; ++q) {
            int e = bid * EBS + q * 256 + tid;
            if (e < NE) {
                int d = dstv[e];
                int b = d >> 7;
                int pos = atomicAdd(&cur[b], 1);
                tmp[pos] = (srcv[e] << 7) | (d & 127);
            }
        }
        return;
    }

    // ---- embed + gemm0 role ----
    int gb = bid - NEB;
    int lane = tid & 63, w = tid >> 6;
    int node0 = gb * 64;

    for (int t = tid; t < 4096; t += 256) {
        int r = t >> 6, f = t & 63;
        int n = node0 + r;
        float v = 0.f;
        if (n < NN) {
            if (f < FIN)       v = x[(size_t)n * FIN + f];
            else if (f < 62)   v = emb_port[(size_t)ports[n] * 32 + (f - FIN)];
            else               v = emb_flags[(size_t)flags[n] * 2 + (f - 62)];
        }
        sf[r * 65 + f] = v;
    }
    __syncthreads();

    int m  = lane & 15;
    int kg = lane >> 4;
    int rloc = w * 16 + m;
    const float* fr = &sf[rloc * 65 + kg * 8];
    bf16x8 a0, a1;
#pragma unroll
    for (int i = 0; i < 8; ++i) {
        a0[i] = (short)f2bf(fr[i]);
        a1[i] = (short)f2bf(fr[32 + i]);
    }

    f32x4 acc0[4], acc1[4];
#pragma unroll
    for (int jt = 0; jt < 4; ++jt) {
        const ushort* wr0 = Wb + ((size_t)(jt * 16 + m)) * 64 + kg * 8;
        const ushort* wr1 = wr0 + (size_t)H * H;
        bf16x8 b00 = *(const bf16x8*)(wr0);
        bf16x8 b01 = *(const bf16x8*)(wr0 + 32);
        bf16x8 b10 = *(const bf16x8*)(wr1);
        bf16x8 b11 = *(const bf16x8*)(wr1 + 32);
        float bias = brel[jt * 16 + m];
        acc0[jt] = f32x4{0.f, 0.f, 0.f, 0.f};
        acc1[jt] = f32x4{bias, bias, bias, bias};
        acc0[jt] = __builtin_amdgcn_mfma_f32_16x16x32_bf16(a0, b00, acc0[jt], 0, 0, 0);
        acc0[jt] = __builtin_amdgcn_mfma_f32_16x16x32_bf16(a1, b01, acc0[jt], 0, 0, 0);
        acc1[jt] = __builtin_amdgcn_mfma_f32_16x16x32_bf16(a0, b10, acc1[jt], 0, 0, 0);
        acc1[jt] = __builtin_amdgcn_mfma_f32_16x16x32_bf16(a1, b11, acc1[jt], 0, 0, 0);
    }

    int nl = w * 16 + kg * 4;

#pragma unroll
    for (int jt = 0; jt < 4; ++jt)
#pragma unroll
        for (int r = 0; r < 4; ++r)
            so[(nl + r) * 65 + jt * 16 + m] = acc0[jt][r];
    __syncthreads();
    for (int t = tid; t < 512; t += 256) {
        int rr = t >> 3, oct = t & 7;
        if (node0 + rr < NN) {
            const float* s = &so[rr * 65 + oct * 8];
            uint4 v;
            v.x = (uint)f2bf(s[0]) | ((uint)f2bf(s[1]) << 16);
            v.y = (uint)f2bf(s[2]) | ((uint)f2bf(s[3]) << 16);
            v.z = (uint)f2bf(s[4]) | ((uint)f2bf(s[5]) << 16);
            v.w = (uint)f2bf(s[6]) | ((uint)f2bf(s[7]) << 16);
            *((uint4*)(z0 + (size_t)node0 * H) + t) = v;
        }
    }
    __syncthreads();

#pragma unroll
    for (int jt = 0; jt < 4; ++jt)
#pragma unroll
        for (int r = 0; r < 4; ++r)
            so[(nl + r) * 65 + jt * 16 + m] = acc1[jt][r];
    __syncthreads();
    for (int t = tid; t < 512; t += 256) {
        int rr = t >> 3, oct = t & 7;
        if (node0 + rr < NN) {
            const float* s = &so[rr * 65 + oct * 8];
            uint4 v;
            v.x = (uint)f2bf(s[0]) | ((uint)f2bf(s[1]) << 16);
            v.y = (uint)f2bf(s[2]) | ((uint)f2bf(s[3]) << 16);
            v.z = (uint)f2bf(s[4]) | ((uint)f2bf(s[5]) << 16);
            v.w = (uint)f2bf(s[6]) | ((uint)f2bf(s[7]) << 16);
            *((uint4*)(z1 + (size_t)node0 * H) + t) = v;
        }
    }
}

// per-bucket counting sort by node with PADDED slots (multiple of 8 per node;
// pad entries point at the zero row) -> edge_arr + node_range.
__global__ __launch_bounds__(256) void bucket_sort_kernel(
    const int* __restrict__ tmp, const int* __restrict__ offs,
    int* __restrict__ edge_arr, int2* __restrict__ node_range)
{
    __shared__ int se[SECAP];
    __shared__ int cnt[128];
    __shared__ int po[128];
    __shared__ int cur[128];
    int b = blockIdx.x, tid = threadIdx.x;
    int start = offs[b * NEB];
    int end   = (b + 1 < NBX) ? offs[(b + 1) * NEB] : NE;
    int ec = end - start; if (ec > SECAP) ec = SECAP;

    if (tid < 128) cnt[tid] = 0;
    __syncthreads();
    for (int t = tid; t < ec; t += 256) {
        int v = tmp[start + t];
        se[t] = v;
        atomicAdd(&cnt[v & 127], 1);
    }
    __syncthreads();
    if (tid < 64) {   // wave 0: exclusive scan of PADDED sizes (2 per lane)
        int c0 = cnt[2 * tid], c1 = cnt[2 * tid + 1];
        int p0 = (c0 + 7) & ~7, p1 = (c1 + 7) & ~7;
        int s = p0 + p1;
        for (int o = 1; o < 64; o <<= 1) {
            int t = __shfl_up(s, o);
            if (tid >= o) s += t;
        }
        po[2 * tid]     = s - p1 - p0;
        po[2 * tid + 1] = s - p1;
        cur[2 * tid]     = s - p1 - p0;
        cur[2 * tid + 1] = s - p1;
    }
    __syncthreads();
    int base = b * PCAP;
    for (int t = tid; t < ec; t += 256) {
        int v = se[t];
        int p = atomicAdd(&cur[v & 127], 1);
        edge_arr[base + p] = v & ~127;       // pure src byte offset
    }
    __syncthreads();
    if (tid < 128) {
        int c = cnt[tid];
        int pd = (c + 7) & ~7;
        for (int q = c; q < pd; ++q)
            edge_arr[base + po[tid] + q] = ZOFF;   // pad -> zero row
        int n = b * 128 + tid;
        if (n < NN) node_range[n] = make_int2(base + po[tid], c);
    }
}

// MFMA GEMMs (layers 1,2)
__global__ __launch_bounds__(256) void gemm_kernel(
    const ushort* __restrict__ h_in, const ushort* __restrict__ Wb,
    const float* __restrict__ brel,
    ushort* __restrict__ z0, ushort* __restrict__ z1)
{
    __shared__ float so[64 * 65];
    int tid = threadIdx.x, lane = tid & 63, w = tid >> 6;
    int m  = lane & 15;
    int kg = lane >> 4;
    int node0 = blockIdx.x * 64 + w * 16;

    int row = node0 + m; if (row >= NN) row = NN - 1;
    const ushort* hr = h_in + (size_t)row * H + kg * 8;
    bf16x8 a0 = *(const bf16x8*)(hr);
    bf16x8 a1 = *(const bf16x8*)(hr + 32);

    f32x4 acc0[4], acc1[4];
#pragma unroll
    for (int jt = 0; jt < 4; ++jt) {
        const ushort* wr0 = Wb + ((size_t)(jt * 16 + m)) * 64 + kg * 8;
        const ushort* wr1 = wr0 + (size_t)H * H;
        bf16x8 b00 = *(const bf16x8*)(wr0);
        bf16x8 b01 = *(const bf16x8*)(wr0 + 32);
        bf16x8 b10 = *(const bf16x8*)(wr1);
        bf16x8 b11 = *(const bf16x8*)(wr1 + 32);
        float bias = brel[jt * 16 + m];
        acc0[jt] = f32x4{0.f, 0.f, 0.f, 0.f};
        acc1[jt] = f32x4{bias, bias, bias, bias};
        acc0[jt] = __builtin_amdgcn_mfma_f32_16x16x32_bf16(a0, b00, acc0[jt], 0, 0, 0);
        acc0[jt] = __builtin_amdgcn_mfma_f32_16x16x32_bf16(a1, b01, acc0[jt], 0, 0, 0);
        acc1[jt] = __builtin_amdgcn_mfma_f32_16x16x32_bf16(a0, b10, acc1[jt], 0, 0, 0);
        acc1[jt] = __builtin_amdgcn_mfma_f32_16x16x32_bf16(a1, b11, acc1[jt], 0, 0, 0);
    }

    int nl = w * 16 + kg * 4;
    int nodeS0 = blockIdx.x * 64;

#pragma unroll
    for (int jt = 0; jt < 4; ++jt)
#pragma unroll
        for (int r = 0; r < 4; ++r)
            so[(nl + r) * 65 + jt * 16 + m] = acc0[jt][r];
    __syncthreads();
    for (int t = tid; t < 512; t += 256) {
        int rr = t >> 3, oct = t & 7;
        if (nodeS0 + rr < NN) {
            const float* s = &so[rr * 65 + oct * 8];
            uint4 v;
            v.x = (uint)f2bf(s[0]) | ((uint)f2bf(s[1]) << 16);
            v.y = (uint)f2bf(s[2]) | ((uint)f2bf(s[3]) << 16);
            v.z = (uint)f2bf(s[4]) | ((uint)f2bf(s[5]) << 16);
            v.w = (uint)f2bf(s[6]) | ((uint)f2bf(s[7]) << 16);
            *((uint4*)(z0 + (size_t)nodeS0 * H) + t) = v;
        }
    }
    __syncthreads();

#pragma unroll
    for (int jt = 0; jt < 4; ++jt)
#pragma unroll
        for (int r = 0; r < 4; ++r)
            so[(nl + r) * 65 + jt * 16 + m] = acc1[jt][r];
    __syncthreads();
    for (int t = tid; t < 512; t += 256) {
        int rr = t >> 3, oct = t & 7;
        if (nodeS0 + rr < NN) {
            const float* s = &so[rr * 65 + oct * 8];
            uint4 v;
            v.x = (uint)f2bf(s[0]) | ((uint)f2bf(s[1]) << 16);
            v.y = (uint)f2bf(s[2]) | ((uint)f2bf(s[3]) << 16);
            v.z = (uint)f2bf(s[4]) | ((uint)f2bf(s[5]) << 16);
            v.w = (uint)f2bf(s[6]) | ((uint)f2bf(s[7]) << 16);
            *((uint4*)(z1 + (size_t)nodeS0 * H) + t) = v;
        }
    }
}

// pure gather, padded edge lists: all loads unconditional (pads hit zero row).
__global__ __launch_bounds__(256) void gather_relu_kernel(
    const ushort* __restrict__ z0, const ushort* __restrict__ z1,
    const int2* __restrict__ node_range, const int* __restrict__ edge_arr,
    ushort* __restrict__ h_out)
{
    int tid = blockIdx.x * 256 + threadIdx.x;
    int n = tid >> 3, oct = tid & 7;
    if (n >= NN) return;
    int2 rng = node_range[n];
    int p0 = rng.x;
    int pend = p0 + ((rng.y + 7) & ~7);
    const char* zb = (const char*)z0 + oct * 16;
    float a[8] = {0.f,0.f,0.f,0.f,0.f,0.f,0.f,0.f};
    for (int p = p0; p < pend; p += 8) {
        uint4 v[8];
#pragma unroll
        for (int q = 0; q < 8; ++q) {
            int o = edge_arr[p + q];
            v[q] = *(const uint4*)(zb + o);
        }
#pragma unroll
        for (int q = 0; q < 8; ++q) {
            a[0] += bf_lo(v[q].x); a[1] += bf_hi(v[q].x);
            a[2] += bf_lo(v[q].y); a[3] += bf_hi(v[q].y);
            a[4] += bf_lo(v[q].z); a[5] += bf_hi(v[q].z);
            a[6] += bf_lo(v[q].w); a[7] += bf_hi(v[q].w);
        }
    }
    uint4 sv = *(const uint4*)((const char*)z1 + (size_t)n * 128 + oct * 16);
    a[0] += bf_lo(sv.x); a[1] += bf_hi(sv.x);
    a[2] += bf_lo(sv.y); a[3] += bf_hi(sv.y);
    a[4] += bf_lo(sv.z); a[5] += bf_hi(sv.z);
    a[6] += bf_lo(sv.w); a[7] += bf_hi(sv.w);
    uint4 o;
    o.x = (uint)f2bf(fmaxf(a[0], 0.f)) | ((uint)f2bf(fmaxf(a[1], 0.f)) << 16);
    o.y = (uint)f2bf(fmaxf(a[2], 0.f)) | ((uint)f2bf(fmaxf(a[3], 0.f)) << 16);
    o.z = (uint)f2bf(fmaxf(a[4], 0.f)) | ((uint)f2bf(fmaxf(a[5], 0.f)) << 16);
    o.w = (uint)f2bf(fmaxf(a[6], 0.f)) | ((uint)f2bf(fmaxf(a[7], 0.f)) << 16);
    *((uint4*)h_out + tid) = o;
}

// fused max-pool + MLP head: one 512-thread block per graph
__global__ __launch_bounds__(512) void pool_mlp_kernel(
    const ushort* __restrict__ h, const int* __restrict__ batch,
    const float* __restrict__ fc1W, const float* __restrict__ fc1b,
    const float* __restrict__ fc2W, const float* __restrict__ fc2b,
    const float* __restrict__ fc3W, const float* __restrict__ fc3b,
    float* __restrict__ out)
{
    __shared__ float red[8][64];
    __shared__ float s0[64];
    __shared__ float s1[64];
    __shared__ float s2[64];
    int b = blockIdx.x;
    int tid = threadIdx.x;
    int f = tid & 63, w = tid >> 6;
    int lo = 0, hi = NN;
    while (lo < hi) { int mid = (lo + hi) >> 1; if (batch[mid] < b) lo = mid + 1; else hi = mid; }
    int lo2 = lo, hi2 = NN;
    while (lo2 < hi2) { int mid = (lo2 + hi2) >> 1; if (batch[mid] < b + 1) lo2 = mid + 1; else hi2 = mid; }
    float m = -3.402823466e38f;
    for (int n = lo + w; n < lo2; n += 8) {
        ushort u = h[(size_t)n * H + f];
        m = fmaxf(m, __uint_as_float((uint)u << 16));
    }
    red[w][f] = m;
    __syncthreads();
    int j = tid;
    if (tid < 64) {
        float mm = red[0][j];
#pragma unroll
        for (int q = 1; q < 8; ++q) mm = fmaxf(mm, red[q][j]);
        s0[j] = mm;
    }
    __syncthreads();
    float acc = 0.f;
    if (tid < 64) {
        acc = fc1b[j];
        for (int k = 0; k < 64; ++k) acc = fmaf(s0[k], fc1W[j * 64 + k], acc);
    }
    __syncthreads();
    if (tid < 64) s1[j] = fmaxf(acc, 0.f);
    __syncthreads();
    if (tid < 64) {
        acc = fc2b[j];
        for (int k = 0; k < 64; ++k) acc = fmaf(s1[k], fc2W[j * 64 + k], acc);
    }
    __syncthreads();
    if (tid < 64) s2[j] = fmaxf(acc, 0.f);
    __syncthreads();
    if (tid < NC) {
        acc = fc3b[j];
        for (int k = 0; k < 64; ++k) acc = fmaf(s2[k], fc3W[j * 64 + k], acc);
        out[b * NC + j] = acc;
    }
}

// ---------------- launcher ----------------

extern "C" void kernel_launch(void* const* d_in, const int* in_sizes, int n_in,
                              void* d_out, int out_size, void* d_ws, size_t ws_size,
                              hipStream_t stream)
{
    const float* x         = (const float*)d_in[0];
    const int*   dst_ports = (const int*)d_in[1];
    const int*   tcp_flags = (const int*)d_in[2];
    const int*   edge_src_in = (const int*)d_in[3];          // row 0 of (2,E)
    const int*   edge_dst_in = edge_src_in + NE;             // row 1
    const int*   batch     = (const int*)d_in[4];
    const float* emb_port  = (const float*)d_in[5];
    const float* emb_flags = (const float*)d_in[6];
    const float* Wrel      = (const float*)d_in[7];
    const float* brel      = (const float*)d_in[8];
    const float* Wroot     = (const float*)d_in[9];
    const float* fc1W      = (const float*)d_in[10];
    const float* fc1b      = (const float*)d_in[11];
    const float* fc2W      = (const float*)d_in[12];
    const float* fc2b      = (const float*)d_in[13];
    const float* fc3W      = (const float*)d_in[14];
    const float* fc3b      = (const float*)d_in[15];
    float* out = (float*)d_out;

    // workspace carve-up (256B aligned)
    char* ws = (char*)d_ws;
    size_t off = 0;
    auto alloc = [&](size_t bytes) {
        void* p = ws + off;
        off += (bytes + 255) & ~(size_t)255;
        return p;
    };
    ushort* hA        = (ushort*)alloc((size_t)NN * H * 2);
    ushort* hB        = (ushort*)alloc((size_t)NN * H * 2);
    ushort* z0        = (ushort*)alloc((size_t)(NN + 1) * H * 2);  // +1 zero row
    ushort* z1        = (ushort*)alloc((size_t)NN * H * 2);
    int*    counts    = (int*)alloc((size_t)NS * 4);      // doubles as offs (in place)
    int*    tmp       = (int*)alloc((size_t)NE * 4);
    int*    edge_arr  = (int*)alloc((size_t)NBX * PCAP * 4);
    int2*   node_range= (int2*)alloc((size_t)NN * 8);
    int*    bsum      = (int*)alloc((size_t)256 * 4);
    ushort* Wb        = (ushort*)alloc((size_t)L * 2 * H * H * 2);

    const int SBLK = (NS + 1023) / 1024;   // 150 scan blocks

    // fused: radix count + weight convert + zero-row init
    count_prep_kernel<<<NEB + 96 + 1, 256, 0, stream>>>(
        edge_dst_in, counts, Wrel, Wroot, Wb, z0);

    // scan of counts
    scanA1_kernel<<<SBLK, 1024, 0, stream>>>(counts, counts, bsum);
    scanA2_kernel<<<1, 256, 0, stream>>>(bsum, SBLK);
    scanA3_kernel<<<SBLK - 1, 1024, 0, stream>>>(counts, bsum);

    // fused: ranked scatter + embed/gemm0 (independent roles, one dispatch)
    const int ggrid = (NN + 63) / 64;   // 782
    scatter_gemm0_kernel<<<NEB + ggrid, 256, 0, stream>>>(
        edge_src_in, edge_dst_in, counts, tmp,
        x, dst_ports, tcp_flags, emb_port, emb_flags, Wb, brel, z0, z1);

    // padded per-bucket sort
    bucket_sort_kernel<<<NBX, 256, 0, stream>>>(tmp, counts, edge_arr, node_range);

    // layer 0 gather, then layers 1,2
    const int agrid = (NN * 8 + 255) / 256;
    gather_relu_kernel<<<agrid, 256, 0, stream>>>(z0, z1, node_range, edge_arr, hA);

    gemm_kernel<<<ggrid, 256, 0, stream>>>(
        hA, Wb + (size_t)1 * 2 * H * H, brel + 1 * H, z0, z1);
    gather_relu_kernel<<<agrid, 256, 0, stream>>>(z0, z1, node_range, edge_arr, hB);
    gemm_kernel<<<ggrid, 256, 0, stream>>>(
        hB, Wb + (size_t)2 * 2 * H * H, brel + 2 * H, z0, z1);
    gather_relu_kernel<<<agrid, 256, 0, stream>>>(z0, z1, node_range, edge_arr, hA);

    // fused global max pool + MLP head
    pool_mlp_kernel<<<NB, 512, 0, stream>>>(
        hA, batch, fc1W, fc1b, fc2W, fc2b, fc3W, fc3b, out);
}

// Round 14
// 240.506 us; speedup vs baseline: 2.1450x; 1.0111x over previous
//
#include <hip/hip_runtime.h>

#define NN 50000
#define NE 800000
#define NB 128
#define FIN 30
#define H 64
#define NC 10
#define L 3

#define EBS 2048              // edges per chunk
#define NEB 391               // ceil(NE / EBS)
#define NBX 391               // dst buckets (dst >> 7), 128 nodes each
#define NS (NBX * NEB)        // counts array size = 152881
#define SECAP 2816            // LDS edge stage capacity per bucket (+17 sigma)
#define PCAP 3456             // padded per-bucket edge_arr stride
#define ZOFF (NN << 7)        // byte offset of the zero row (row NN of z0)

typedef unsigned int uint;
typedef unsigned short ushort;
typedef __attribute__((ext_vector_type(8))) short bf16x8;
typedef __attribute__((ext_vector_type(4))) float f32x4;

// f32 -> bf16 round-to-nearest-even (finite inputs)
__device__ __forceinline__ ushort f2bf(float x) {
    uint u = __float_as_uint(x);
    u += 0x7fffu + ((u >> 16) & 1u);
    return (ushort)(u >> 16);
}
__device__ __forceinline__ float bf_lo(uint v) { return __uint_as_float(v << 16); }
__device__ __forceinline__ float bf_hi(uint v) { return __uint_as_float(v & 0xffff0000u); }

// ---------------- kernels ----------------

// fused: blocks [0,NEB) = radix count; [NEB, NEB+96) = weight bf16 convert;
// block NEB+96 = zero-row init for gather padding.
__global__ __launch_bounds__(256) void count_prep_kernel(
    const int* __restrict__ dst, int* __restrict__ counts,
    const float* __restrict__ Wrel, const float* __restrict__ Wroot,
    ushort* __restrict__ Wb, ushort* __restrict__ z0)
{
    __shared__ int cnt[NBX];
    int bid = blockIdx.x, tid = threadIdx.x;
    if (bid < NEB) {
        for (int t = tid; t < NBX; t += 256) cnt[t] = 0;
        __syncthreads();
#pragma unroll
        for (int q = 0; q < 8; ++q) {
            int e = bid * EBS + q * 256 + tid;
            if (e < NE) atomicAdd(&cnt[dst[e] >> 7], 1);
        }
        __syncthreads();
        for (int t = tid; t < NBX; t += 256) counts[t * NEB + bid] = cnt[t];
    } else if (bid < NEB + 96) {
        int t = (bid - NEB) * 256 + tid;
        if (t < L * 2 * H * H) {
            int l = t / (2 * H * H), rem = t % (2 * H * H);
            int mat = rem / (H * H), jk = rem % (H * H);
            const float* W = mat ? Wroot : Wrel;
            Wb[t] = f2bf(W[l * H * H + jk]);
        }
    } else {
        if (tid < 8) ((uint4*)(z0 + (size_t)NN * H))[tid] = make_uint4(0u, 0u, 0u, 0u);
    }
}

// exclusive scan over counts[NS]: per-block exclusive + block totals
__global__ __launch_bounds__(1024) void scanA1_kernel(
    const int* __restrict__ counts, int* __restrict__ offs, int* __restrict__ bsum)
{
    __shared__ int wsum[16];
    int i = blockIdx.x * 1024 + threadIdx.x;
    int lane = threadIdx.x & 63;
    int wv = threadIdx.x >> 6;
    int v = (i < NS) ? counts[i] : 0;
    int s = v;
    for (int off = 1; off < 64; off <<= 1) {
        int t = __shfl_up(s, off);
        if (lane >= off) s += t;
    }
    if (lane == 63) wsum[wv] = s;
    __syncthreads();
    if (wv == 0) {
        int ws = (lane < 16) ? wsum[lane] : 0;
        for (int off = 1; off < 16; off <<= 1) {
            int t = __shfl_up(ws, off);
            if (lane >= off) ws += t;
        }
        if (lane < 16) wsum[lane] = ws;
    }
    __syncthreads();
    int base = (wv > 0) ? wsum[wv - 1] : 0;
    s += base;
    if (i < NS) offs[i] = s - v;
    if (threadIdx.x == 1023) bsum[blockIdx.x] = s;
}

// fused carry-add: each block (b=1..SBLK-1) re-scans the 150 block totals in
// LDS (cheap) and adds the exclusive carry to its offs chunk. Replaces the
// old scanA2+scanA3 pair.
__global__ __launch_bounds__(1024) void scanB_kernel(
    int* __restrict__ offs, const int* __restrict__ bsum, int nblk)
{
    __shared__ int arr[256];
    int tid = threadIdx.x;
    int b = blockIdx.x + 1;
    if (tid < 256) arr[tid] = (tid < nblk) ? bsum[tid] : 0;
    __syncthreads();
    // Hillis-Steele inclusive scan of 256 entries (first 256 threads active)
    for (int off = 1; off < 256; off <<= 1) {
        int u = 0;
        if (tid < 256 && tid >= off) u = arr[tid - off];
        __syncthreads();
        if (tid < 256) arr[tid] += u;
        __syncthreads();
    }
    int carry = arr[b - 1];           // inclusive sum of blocks 0..b-1
    int i = b * 1024 + tid;
    if (i < NS) offs[i] += carry;
}

// fused: blocks [0,NEB) = ranked scatter; [NEB, NEB+782) = embed+MFMA gemm0.
// LDS: single 64*65 float buffer, unioned across roles and phases -> 17 KB.
__global__ __launch_bounds__(256) void scatter_gemm0_kernel(
    const int* __restrict__ srcv, const int* __restrict__ dstv,
    const int* __restrict__ offs, int* __restrict__ tmp,
    const float* __restrict__ x, const int* __restrict__ ports,
    const int* __restrict__ flags, const float* __restrict__ emb_port,
    const float* __restrict__ emb_flags,
    const ushort* __restrict__ Wb, const float* __restrict__ brel,
    ushort* __restrict__ z0, ushort* __restrict__ z1)
{
    __shared__ float buf[64 * 65];    // union: cur[] | sf | so
    int bid = blockIdx.x, tid = threadIdx.x;

    if (bid < NEB) {
        // ---- ranked scatter role (uses buf as int cursor array) ----
        int* cur = (int*)buf;
        for (int t = tid; t < NBX; t += 256) cur[t] = offs[t * NEB + bid];
        __syncthreads();
#pragma unroll
        for (int q = 0; q < 8; ++q) {
            int e = bid * EBS + q * 256 + tid;
            if (e < NE) {
                int d = dstv[e];
                int b = d >> 7;
                int pos = atomicAdd(&cur[b], 1);
                tmp[pos] = (srcv[e] << 7) | (d & 127);
            }
        }
        return;
    }

    // ---- embed + gemm0 role ----
    int gb = bid - NEB;
    int lane = tid & 63, w = tid >> 6;
    int node0 = gb * 64;

    for (int t = tid; t < 4096; t += 256) {
        int r = t >> 6, f = t & 63;
        int n = node0 + r;
        float v = 0.f;
        if (n < NN) {
            if (f < FIN)       v = x[(size_t)n * FIN + f];
            else if (f < 62)   v = emb_port[(size_t)ports[n] * 32 + (f - FIN)];
            else               v = emb_flags[(size_t)flags[n] * 2 + (f - 62)];
        }
        buf[r * 65 + f] = v;
    }
    __syncthreads();

    int m  = lane & 15;
    int kg = lane >> 4;
    int rloc = w * 16 + m;
    const float* fr = &buf[rloc * 65 + kg * 8];
    bf16x8 a0, a1;
#pragma unroll
    for (int i = 0; i < 8; ++i) {
        a0[i] = (short)f2bf(fr[i]);
        a1[i] = (short)f2bf(fr[32 + i]);
    }
    __syncthreads();   // all sf reads done; buf reusable as output stage

    f32x4 acc0[4], acc1[4];
#pragma unroll
    for (int jt = 0; jt < 4; ++jt) {
        const ushort* wr0 = Wb + ((size_t)(jt * 16 + m)) * 64 + kg * 8;
        const ushort* wr1 = wr0 + (size_t)H * H;
        bf16x8 b00 = *(const bf16x8*)(wr0);
        bf16x8 b01 = *(const bf16x8*)(wr0 + 32);
        bf16x8 b10 = *(const bf16x8*)(wr1);
        bf16x8 b11 = *(const bf16x8*)(wr1 + 32);
        float bias = brel[jt * 16 + m];
        acc0[jt] = f32x4{0.f, 0.f, 0.f, 0.f};
        acc1[jt] = f32x4{bias, bias, bias, bias};
        acc0[jt] = __builtin_amdgcn_mfma_f32_16x16x32_bf16(a0, b00, acc0[jt], 0, 0, 0);
        acc0[jt] = __builtin_amdgcn_mfma_f32_16x16x32_bf16(a1, b01, acc0[jt], 0, 0, 0);
        acc1[jt] = __builtin_amdgcn_mfma_f32_16x16x32_bf16(a0, b10, acc1[jt], 0, 0, 0);
        acc1[jt] = __builtin_amdgcn_mfma_f32_16x16x32_bf16(a1, b11, acc1[jt], 0, 0, 0);
    }

    int nl = w * 16 + kg * 4;

#pragma unroll
    for (int jt = 0; jt < 4; ++jt)
#pragma unroll
        for (int r = 0; r < 4; ++r)
            buf[(nl + r) * 65 + jt * 16 + m] = acc0[jt][r];
    __syncthreads();
    for (int t = tid; t < 512; t += 256) {
        int rr = t >> 3, oct = t & 7;
        if (node0 + rr < NN) {
            const float* s = &buf[rr * 65 + oct * 8];
            uint4 v;
            v.x = (uint)f2bf(s[0]) | ((uint)f2bf(s[1]) << 16);
            v.y = (uint)f2bf(s[2]) | ((uint)f2bf(s[3]) << 16);
            v.z = (uint)f2bf(s[4]) | ((uint)f2bf(s[5]) << 16);
            v.w = (uint)f2bf(s[6]) | ((uint)f2bf(s[7]) << 16);
            *((uint4*)(z0 + (size_t)node0 * H) + t) = v;
        }
    }
    __syncthreads();

#pragma unroll
    for (int jt = 0; jt < 4; ++jt)
#pragma unroll
        for (int r = 0; r < 4; ++r)
            buf[(nl + r) * 65 + jt * 16 + m] = acc1[jt][r];
    __syncthreads();
    for (int t = tid; t < 512; t += 256) {
        int rr = t >> 3, oct = t & 7;
        if (node0 + rr < NN) {
            const float* s = &buf[rr * 65 + oct * 8];
            uint4 v;
            v.x = (uint)f2bf(s[0]) | ((uint)f2bf(s[1]) << 16);
            v.y = (uint)f2bf(s[2]) | ((uint)f2bf(s[3]) << 16);
            v.z = (uint)f2bf(s[4]) | ((uint)f2bf(s[5]) << 16);
            v.w = (uint)f2bf(s[6]) | ((uint)f2bf(s[7]) << 16);
            *((uint4*)(z1 + (size_t)node0 * H) + t) = v;
        }
    }
}

// per-bucket counting sort by node with PADDED slots (multiple of 8 per node;
// pads point at the zero row) -> edge_arr + node_range (start, padded_count).
__global__ __launch_bounds__(256) void bucket_sort_kernel(
    const int* __restrict__ tmp, const int* __restrict__ offs,
    int* __restrict__ edge_arr, int2* __restrict__ node_range)
{
    __shared__ int se[SECAP];
    __shared__ int cnt[128];
    __shared__ int po[128];
    __shared__ int cur[128];
    int b = blockIdx.x, tid = threadIdx.x;
    int start = offs[b * NEB];
    int end   = (b + 1 < NBX) ? offs[(b + 1) * NEB] : NE;
    int ec = end - start; if (ec > SECAP) ec = SECAP;

    if (tid < 128) cnt[tid] = 0;
    __syncthreads();
    for (int t = tid; t < ec; t += 256) {
        int v = tmp[start + t];
        se[t] = v;
        atomicAdd(&cnt[v & 127], 1);
    }
    __syncthreads();
    if (tid < 64) {   // wave 0: exclusive scan of PADDED sizes (2 per lane)
        int c0 = cnt[2 * tid], c1 = cnt[2 * tid + 1];
        int p0 = (c0 + 7) & ~7, p1 = (c1 + 7) & ~7;
        int s = p0 + p1;
        for (int o = 1; o < 64; o <<= 1) {
            int t = __shfl_up(s, o);
            if (tid >= o) s += t;
        }
        po[2 * tid]     = s - p1 - p0;
        po[2 * tid + 1] = s - p1;
        cur[2 * tid]     = s - p1 - p0;
        cur[2 * tid + 1] = s - p1;
    }
    __syncthreads();
    int base = b * PCAP;
    for (int t = tid; t < ec; t += 256) {
        int v = se[t];
        int p = atomicAdd(&cur[v & 127], 1);
        edge_arr[base + p] = v & ~127;       // pure src byte offset
    }
    __syncthreads();
    if (tid < 128) {
        int c = cnt[tid];
        int pd = (c + 7) & ~7;
        for (int q = c; q < pd; ++q)
            edge_arr[base + po[tid] + q] = ZOFF;   // pad -> zero row
        int n = b * 128 + tid;
        if (n < NN) node_range[n] = make_int2(base + po[tid], pd);
    }
}

// MFMA GEMMs (layers 1,2); single unioned LDS buffer (17 KB)
__global__ __launch_bounds__(256) void gemm_kernel(
    const ushort* __restrict__ h_in, const ushort* __restrict__ Wb,
    const float* __restrict__ brel,
    ushort* __restrict__ z0, ushort* __restrict__ z1)
{
    __shared__ float so[64 * 65];
    int tid = threadIdx.x, lane = tid & 63, w = tid >> 6;
    int m  = lane & 15;
    int kg = lane >> 4;
    int node0 = blockIdx.x * 64 + w * 16;

    int row = node0 + m; if (row >= NN) row = NN - 1;
    const ushort* hr = h_in + (size_t)row * H + kg * 8;
    bf16x8 a0 = *(const bf16x8*)(hr);
    bf16x8 a1 = *(const bf16x8*)(hr + 32);

    f32x4 acc0[4], acc1[4];
#pragma unroll
    for (int jt = 0; jt < 4; ++jt) {
        const ushort* wr0 = Wb + ((size_t)(jt * 16 + m)) * 64 + kg * 8;
        const ushort* wr1 = wr0 + (size_t)H * H;
        bf16x8 b00 = *(const bf16x8*)(wr0);
        bf16x8 b01 = *(const bf16x8*)(wr0 + 32);
        bf16x8 b10 = *(const bf16x8*)(wr1);
        bf16x8 b11 = *(const bf16x8*)(wr1 + 32);
        float bias = brel[jt * 16 + m];
        acc0[jt] = f32x4{0.f, 0.f, 0.f, 0.f};
        acc1[jt] = f32x4{bias, bias, bias, bias};
        acc0[jt] = __builtin_amdgcn_mfma_f32_16x16x32_bf16(a0, b00, acc0[jt], 0, 0, 0);
        acc0[jt] = __builtin_amdgcn_mfma_f32_16x16x32_bf16(a1, b01, acc0[jt], 0, 0, 0);
        acc1[jt] = __builtin_amdgcn_mfma_f32_16x16x32_bf16(a0, b10, acc1[jt], 0, 0, 0);
        acc1[jt] = __builtin_amdgcn_mfma_f32_16x16x32_bf16(a1, b11, acc1[jt], 0, 0, 0);
    }

    int nl = w * 16 + kg * 4;
    int nodeS0 = blockIdx.x * 64;

#pragma unroll
    for (int jt = 0; jt < 4; ++jt)
#pragma unroll
        for (int r = 0; r < 4; ++r)
            so[(nl + r) * 65 + jt * 16 + m] = acc0[jt][r];
    __syncthreads();
    for (int t = tid; t < 512; t += 256) {
        int rr = t >> 3, oct = t & 7;
        if (nodeS0 + rr < NN) {
            const float* s = &so[rr * 65 + oct * 8];
            uint4 v;
            v.x = (uint)f2bf(s[0]) | ((uint)f2bf(s[1]) << 16);
            v.y = (uint)f2bf(s[2]) | ((uint)f2bf(s[3]) << 16);
            v.z = (uint)f2bf(s[4]) | ((uint)f2bf(s[5]) << 16);
            v.w = (uint)f2bf(s[6]) | ((uint)f2bf(s[7]) << 16);
            *((uint4*)(z0 + (size_t)nodeS0 * H) + t) = v;
        }
    }
    __syncthreads();

#pragma unroll
    for (int jt = 0; jt < 4; ++jt)
#pragma unroll
        for (int r = 0; r < 4; ++r)
            so[(nl + r) * 65 + jt * 16 + m] = acc1[jt][r];
    __syncthreads();
    for (int t = tid; t < 512; t += 256) {
        int rr = t >> 3, oct = t & 7;
        if (nodeS0 + rr < NN) {
            const float* s = &so[rr * 65 + oct * 8];
            uint4 v;
            v.x = (uint)f2bf(s[0]) | ((uint)f2bf(s[1]) << 16);
            v.y = (uint)f2bf(s[2]) | ((uint)f2bf(s[3]) << 16);
            v.z = (uint)f2bf(s[4]) | ((uint)f2bf(s[5]) << 16);
            v.w = (uint)f2bf(s[6]) | ((uint)f2bf(s[7]) << 16);
            *((uint4*)(z1 + (size_t)nodeS0 * H) + t) = v;
        }
    }
}

// pure gather, padded edge lists: all loads unconditional (pads hit zero row).
__global__ __launch_bounds__(256) void gather_relu_kernel(
    const ushort* __restrict__ z0, const ushort* __restrict__ z1,
    const int2* __restrict__ node_range, const int* __restrict__ edge_arr,
    ushort* __restrict__ h_out)
{
    int tid = blockIdx.x * 256 + threadIdx.x;
    int n = tid >> 3, oct = tid & 7;
    if (n >= NN) return;
    int2 rng = node_range[n];
    int p0 = rng.x;
    int pend = p0 + rng.y;             // rng.y already padded to x8
    const char* zb = (const char*)z0 + oct * 16;
    float a[8] = {0.f,0.f,0.f,0.f,0.f,0.f,0.f,0.f};
    for (int p = p0; p < pend; p += 8) {
        uint4 v[8];
#pragma unroll
        for (int q = 0; q < 8; ++q) {
            int o = edge_arr[p + q];
            v[q] = *(const uint4*)(zb + o);
        }
#pragma unroll
        for (int q = 0; q < 8; ++q) {
            a[0] += bf_lo(v[q].x); a[1] += bf_hi(v[q].x);
            a[2] += bf_lo(v[q].y); a[3] += bf_hi(v[q].y);
            a[4] += bf_lo(v[q].z); a[5] += bf_hi(v[q].z);
            a[6] += bf_lo(v[q].w); a[7] += bf_hi(v[q].w);
        }
    }
    uint4 sv = *(const uint4*)((const char*)z1 + (size_t)n * 128 + oct * 16);
    a[0] += bf_lo(sv.x); a[1] += bf_hi(sv.x);
    a[2] += bf_lo(sv.y); a[3] += bf_hi(sv.y);
    a[4] += bf_lo(sv.z); a[5] += bf_hi(sv.z);
    a[6] += bf_lo(sv.w); a[7] += bf_hi(sv.w);
    uint4 o;
    o.x = (uint)f2bf(fmaxf(a[0], 0.f)) | ((uint)f2bf(fmaxf(a[1], 0.f)) << 16);
    o.y = (uint)f2bf(fmaxf(a[2], 0.f)) | ((uint)f2bf(fmaxf(a[3], 0.f)) << 16);
    o.z = (uint)f2bf(fmaxf(a[4], 0.f)) | ((uint)f2bf(fmaxf(a[5], 0.f)) << 16);
    o.w = (uint)f2bf(fmaxf(a[6], 0.f)) | ((uint)f2bf(fmaxf(a[7], 0.f)) << 16);
    *((uint4*)h_out + tid) = o;
}

// fused max-pool + MLP head: one 512-thread block per graph
__global__ __launch_bounds__(512) void pool_mlp_kernel(
    const ushort* __restrict__ h, const int* __restrict__ batch,
    const float* __restrict__ fc1W, const float* __restrict__ fc1b,
    const float* __restrict__ fc2W, const float* __restrict__ fc2b,
    const float* __restrict__ fc3W, const float* __restrict__ fc3b,
    float* __restrict__ out)
{
    __shared__ float red[8][64];
    __shared__ float s0[64];
    __shared__ float s1[64];
    __shared__ float s2[64];
    int b = blockIdx.x;
    int tid = threadIdx.x;
    int f = tid & 63, w = tid >> 6;
    int lo = 0, hi = NN;
    while (lo < hi) { int mid = (lo + hi) >> 1; if (batch[mid] < b) lo = mid + 1; else hi = mid; }
    int lo2 = lo, hi2 = NN;
    while (lo2 < hi2) { int mid = (lo2 + hi2) >> 1; if (batch[mid] < b + 1) lo2 = mid + 1; else hi2 = mid; }
    float m = -3.402823466e38f;
    for (int n = lo + w; n < lo2; n += 8) {
        ushort u = h[(size_t)n * H + f];
        m = fmaxf(m, __uint_as_float((uint)u << 16));
    }
    red[w][f] = m;
    __syncthreads();
    int j = tid;
    if (tid < 64) {
        float mm = red[0][j];
#pragma unroll
        for (int q = 1; q < 8; ++q) mm = fmaxf(mm, red[q][j]);
        s0[j] = mm;
    }
    __syncthreads();
    float acc = 0.f;
    if (tid < 64) {
        acc = fc1b[j];
        for (int k = 0; k < 64; ++k) acc = fmaf(s0[k], fc1W[j * 64 + k], acc);
    }
    __syncthreads();
    if (tid < 64) s1[j] = fmaxf(acc, 0.f);
    __syncthreads();
    if (tid < 64) {
        acc = fc2b[j];
        for (int k = 0; k < 64; ++k) acc = fmaf(s1[k], fc2W[j * 64 + k], acc);
    }
    __syncthreads();
    if (tid < 64) s2[j] = fmaxf(acc, 0.f);
    __syncthreads();
    if (tid < NC) {
        acc = fc3b[j];
        for (int k = 0; k < 64; ++k) acc = fmaf(s2[k], fc3W[j * 64 + k], acc);
        out[b * NC + j] = acc;
    }
}

// ---------------- launcher ----------------

extern "C" void kernel_launch(void* const* d_in, const int* in_sizes, int n_in,
                              void* d_out, int out_size, void* d_ws, size_t ws_size,
                              hipStream_t stream)
{
    const float* x         = (const float*)d_in[0];
    const int*   dst_ports = (const int*)d_in[1];
    const int*   tcp_flags = (const int*)d_in[2];
    const int*   edge_src_in = (const int*)d_in[3];          // row 0 of (2,E)
    const int*   edge_dst_in = edge_src_in + NE;             // row 1
    const int*   batch     = (const int*)d_in[4];
    const float* emb_port  = (const float*)d_in[5];
    const float* emb_flags = (const float*)d_in[6];
    const float* Wrel      = (const float*)d_in[7];
    const float* brel      = (const float*)d_in[8];
    const float* Wroot     = (const float*)d_in[9];
    const float* fc1W      = (const float*)d_in[10];
    const float* fc1b      = (const float*)d_in[11];
    const float* fc2W      = (const float*)d_in[12];
    const float* fc2b      = (const float*)d_in[13];
    const float* fc3W      = (const float*)d_in[14];
    const float* fc3b      = (const float*)d_in[15];
    float* out = (float*)d_out;

    // workspace carve-up (256B aligned)
    char* ws = (char*)d_ws;
    size_t off = 0;
    auto alloc = [&](size_t bytes) {
        void* p = ws + off;
        off += (bytes + 255) & ~(size_t)255;
        return p;
    };
    ushort* hA        = (ushort*)alloc((size_t)NN * H * 2);
    ushort* hB        = (ushort*)alloc((size_t)NN * H * 2);
    ushort* z0        = (ushort*)alloc((size_t)(NN + 1) * H * 2);  // +1 zero row
    ushort* z1        = (ushort*)alloc((size_t)NN * H * 2);
    int*    counts    = (int*)alloc((size_t)NS * 4);      // doubles as offs (in place)
    int*    tmp       = (int*)alloc((size_t)NE * 4);
    int*    edge_arr  = (int*)alloc((size_t)NBX * PCAP * 4);
    int2*   node_range= (int2*)alloc((size_t)NN * 8);
    int*    bsum      = (int*)alloc((size_t)256 * 4);
    ushort* Wb        = (ushort*)alloc((size_t)L * 2 * H * H * 2);

    const int SBLK = (NS + 1023) / 1024;   // 150 scan blocks

    // fused: radix count + weight convert + zero-row init
    count_prep_kernel<<<NEB + 96 + 1, 256, 0, stream>>>(
        edge_dst_in, counts, Wrel, Wroot, Wb, z0);

    // scan of counts (2 kernels)
    scanA1_kernel<<<SBLK, 1024, 0, stream>>>(counts, counts, bsum);
    scanB_kernel<<<SBLK - 1, 1024, 0, stream>>>(counts, bsum, SBLK);

    // fused: ranked scatter + embed/gemm0 (independent roles, one dispatch)
    const int ggrid = (NN + 63) / 64;   // 782
    scatter_gemm0_kernel<<<NEB + ggrid, 256, 0, stream>>>(
        edge_src_in, edge_dst_in, counts, tmp,
        x, dst_ports, tcp_flags, emb_port, emb_flags, Wb, brel, z0, z1);

    // padded per-bucket sort
    bucket_sort_kernel<<<NBX, 256, 0, stream>>>(tmp, counts, edge_arr, node_range);

    // layer 0 gather, then layers 1,2
    const int agrid = (NN * 8 + 255) / 256;
    gather_relu_kernel<<<agrid, 256, 0, stream>>>(z0, z1, node_range, edge_arr, hA);

    gemm_kernel<<<ggrid, 256, 0, stream>>>(
        hA, Wb + (size_t)1 * 2 * H * H, brel + 1 * H, z0, z1);
    gather_relu_kernel<<<agrid, 256, 0, stream>>>(z0, z1, node_range, edge_arr, hB);
    gemm_kernel<<<ggrid, 256, 0, stream>>>(
        hB, Wb + (size_t)2 * 2 * H * H, brel + 2 * H, z0, z1);
    gather_relu_kernel<<<agrid, 256, 0, stream>>>(z0, z1, node_range, edge_arr, hA);

    // fused global max pool + MLP head
    pool_mlp_kernel<<<NB, 512, 0, stream>>>(
        hA, batch, fc1W, fc1b, fc2W, fc2b, fc3W, fc3b, out);
}